// Round 1
// baseline (411.297 us; speedup 1.0000x reference)
//
#include <hip/hip_runtime.h>

constexpr int Bn = 32;
constexpr int Cn = 128;
constexpr int Mn = 4000;
constexpr int Gn = 4;
constexpr int Dn = 32;   // C / G
constexpr float GN_EPS = 1e-5f;
constexpr float IN_EPS = 1e-3f;
constexpr float BN_EPS = 1e-5f;

// ---------------------------------------------------------------------------
// GEMM: out[b,o,m] = sum_c W[o,c] * f(in[b,c,m]) (+bias) (+yadd)
// MODE 0: plain (GEMM1)
// MODE 1: +bias, accumulate per-(b,o) sum/sumsq atomically (GEMM2)
// MODE 2: input transform relu(Atr*in+Btr), +bias, +yadd (GEMM3)
// ---------------------------------------------------------------------------
template <int MODE>
__launch_bounds__(256)
__global__ void gemm_kernel(const float* __restrict__ W,
                            const float* __restrict__ in,
                            float* __restrict__ out,
                            const float* __restrict__ bias,
                            const float* __restrict__ Atr,
                            const float* __restrict__ Btr,
                            const float* __restrict__ yadd,
                            float* __restrict__ sum1,
                            float* __restrict__ sum2)
{
    __shared__ float Wl[16][64];
    __shared__ float Il[16][64];
    const int b  = blockIdx.z;
    const int ob = blockIdx.y * 64;
    const int mb = blockIdx.x * 64;
    const int tid = threadIdx.x;
    const int ty = tid >> 4, tx = tid & 15;
    const float* inb = in + (size_t)b * Cn * Mn;

    const int lo  = tid >> 2;        // 0..63 W row in tile
    const int lkq = (tid & 3) * 4;   // 0,4,8,12
    const int lk  = tid >> 4;        // 0..15 input row in tile
    const int lmq = (tid & 15) * 4;  // 0..60

    float acc[4][4] = {};

    for (int kb = 0; kb < Cn; kb += 16) {
        float4 w4 = *(const float4*)(W + (size_t)(ob + lo) * Cn + kb + lkq);
        float4 v4;
        const int gm = mb + lmq;
        if (gm < Mn) v4 = *(const float4*)(inb + (size_t)(kb + lk) * Mn + gm);
        else         v4 = make_float4(0.f, 0.f, 0.f, 0.f);
        if (MODE == 2) {
            const float a  = Atr[b * Cn + kb + lk];
            const float bb = Btr[b * Cn + kb + lk];
            v4.x = fmaxf(fmaf(a, v4.x, bb), 0.f);
            v4.y = fmaxf(fmaf(a, v4.y, bb), 0.f);
            v4.z = fmaxf(fmaf(a, v4.z, bb), 0.f);
            v4.w = fmaxf(fmaf(a, v4.w, bb), 0.f);
        }
        Wl[lkq + 0][lo] = w4.x;
        Wl[lkq + 1][lo] = w4.y;
        Wl[lkq + 2][lo] = w4.z;
        Wl[lkq + 3][lo] = w4.w;
        *(float4*)&Il[lk][lmq] = v4;
        __syncthreads();
#pragma unroll
        for (int k = 0; k < 16; ++k) {
            const float4 a4 = *(const float4*)&Wl[k][ty * 4];
            const float4 b4 = *(const float4*)&Il[k][tx * 4];
            const float av[4] = {a4.x, a4.y, a4.z, a4.w};
            const float bv[4] = {b4.x, b4.y, b4.z, b4.w};
#pragma unroll
            for (int i = 0; i < 4; ++i)
#pragma unroll
                for (int j = 0; j < 4; ++j)
                    acc[i][j] = fmaf(av[i], bv[j], acc[i][j]);
        }
        __syncthreads();
    }

    float ssum[4] = {0.f, 0.f, 0.f, 0.f}, sqsum[4] = {0.f, 0.f, 0.f, 0.f};
    const int m0 = mb + tx * 4;
#pragma unroll
    for (int i = 0; i < 4; ++i) {
        const int o = ob + ty * 4 + i;
        const float bv = (MODE >= 1) ? bias[o] : 0.f;
        const size_t base = (size_t)b * Cn * Mn + (size_t)o * Mn + m0;
        if (m0 + 3 < Mn) {
            float4 r;
            r.x = acc[i][0] + bv;
            r.y = acc[i][1] + bv;
            r.z = acc[i][2] + bv;
            r.w = acc[i][3] + bv;
            if (MODE == 2) {
                const float4 y4 = *(const float4*)(yadd + base);
                r.x += y4.x; r.y += y4.y; r.z += y4.z; r.w += y4.w;
            }
            *(float4*)(out + base) = r;
            if (MODE == 1) {
                ssum[i]  = r.x + r.y + r.z + r.w;
                sqsum[i] = r.x * r.x + r.y * r.y + r.z * r.z + r.w * r.w;
            }
        } else {
#pragma unroll
            for (int j = 0; j < 4; ++j) {
                if (m0 + j < Mn) {
                    float r = acc[i][j] + bv;
                    if (MODE == 2) r += yadd[base + j];
                    out[base + j] = r;
                    if (MODE == 1) { ssum[i] += r; sqsum[i] += r * r; }
                }
            }
        }
    }
    if (MODE == 1) {
#pragma unroll
        for (int i = 0; i < 4; ++i) {
            float s = ssum[i], q = sqsum[i];
#pragma unroll
            for (int d = 1; d < 16; d <<= 1) {
                s += __shfl_xor(s, d);
                q += __shfl_xor(q, d);
            }
            if (tx == 0) {
                const int o = ob + ty * 4 + i;
                atomicAdd(&sum1[b * Cn + o], s);
                atomicAdd(&sum2[b * Cn + o], q);
            }
        }
    }
}

// ---------------------------------------------------------------------------
// Covariance (raw second moments) + per-channel sums of f, f^2, f*x, x, x^2.
// cov_raw[b,g,i,j] = sum_m f_i f_j   (mean correction applied in sqrtm kernel)
// grid: (CSPLIT, G, B)
// ---------------------------------------------------------------------------
constexpr int CSPLIT = 8;
constexpr int CSEG = Mn / CSPLIT;  // 500
constexpr int CTM = 100;
constexpr int CST = 108;           // padded LDS stride (16B aligned, spreads banks)

__launch_bounds__(256)
__global__ void cov_kernel(const float* __restrict__ feat, const float* __restrict__ x,
                           float* __restrict__ cov,
                           float* __restrict__ sf, float* __restrict__ sf2,
                           float* __restrict__ sfx, float* __restrict__ sx,
                           float* __restrict__ sx2)
{
    __shared__ float fl[Dn][CST];
    __shared__ float xl[Dn][CST];
    const int sp = blockIdx.x, g = blockIdx.y, b = blockIdx.z;
    const int tid = threadIdx.x;
    const size_t rowbase = ((size_t)b * Cn + g * Dn) * Mn + sp * CSEG;
    const float* fb = feat + rowbase;
    const float* xb = x + rowbase;
    const int ei  = (tid * 4) >> 5;
    const int ej0 = (tid * 4) & 31;
    const int sc = tid & 31, sseg = tid >> 5;
    float acc[4] = {0.f, 0.f, 0.f, 0.f};
    float cf = 0.f, cf2 = 0.f, cfx = 0.f, cx = 0.f, cx2 = 0.f;

    for (int t0 = 0; t0 < CSEG; t0 += CTM) {
        for (int idx = tid; idx < Dn * CTM; idx += 256) {
            const int r = idx / CTM, ml = idx - r * CTM;
            fl[r][ml] = fb[(size_t)r * Mn + t0 + ml];
            xl[r][ml] = xb[(size_t)r * Mn + t0 + ml];
        }
        __syncthreads();
        for (int ml = sseg; ml < CTM; ml += 8) {
            const float fv = fl[sc][ml], xv = xl[sc][ml];
            cf += fv; cf2 = fmaf(fv, fv, cf2); cfx = fmaf(fv, xv, cfx);
            cx += xv; cx2 = fmaf(xv, xv, cx2);
        }
        for (int m4 = 0; m4 < CTM / 4; ++m4) {
            const float4 fi = *(const float4*)&fl[ei][m4 * 4];
#pragma unroll
            for (int q = 0; q < 4; ++q) {
                const float4 fj = *(const float4*)&fl[ej0 + q][m4 * 4];
                acc[q] = fmaf(fi.x, fj.x, acc[q]);
                acc[q] = fmaf(fi.y, fj.y, acc[q]);
                acc[q] = fmaf(fi.z, fj.z, acc[q]);
                acc[q] = fmaf(fi.w, fj.w, acc[q]);
            }
        }
        __syncthreads();
    }
    float* cvp = cov + (size_t)(b * Gn + g) * (Dn * Dn) + ei * Dn + ej0;
#pragma unroll
    for (int q = 0; q < 4; ++q) atomicAdd(cvp + q, acc[q]);
    const int ch = b * Cn + g * Dn + sc;
    atomicAdd(&sf[ch], cf);
    atomicAdd(&sf2[ch], cf2);
    atomicAdd(&sfx[ch], cfx);
    atomicAdd(&sx[ch], cx);
    atomicAdd(&sx2[ch], cx2);
}

// ---------------------------------------------------------------------------
// Newton-Schulz sqrtm per (b,g) 32x32 + row-mean -> s[b,c]
// ---------------------------------------------------------------------------
__device__ __forceinline__ void mm32(float (*A)[33], float (*Bm)[33],
                                     float (*O)[33], int ei, int ej0)
{
    float a0 = 0.f, a1 = 0.f, a2 = 0.f, a3 = 0.f;
#pragma unroll
    for (int k = 0; k < 32; ++k) {
        const float a = A[ei][k];
        a0 = fmaf(a, Bm[k][ej0 + 0], a0);
        a1 = fmaf(a, Bm[k][ej0 + 1], a1);
        a2 = fmaf(a, Bm[k][ej0 + 2], a2);
        a3 = fmaf(a, Bm[k][ej0 + 3], a3);
    }
    O[ei][ej0 + 0] = a0;
    O[ei][ej0 + 1] = a1;
    O[ei][ej0 + 2] = a2;
    O[ei][ej0 + 3] = a3;
    __syncthreads();
}

__launch_bounds__(256)
__global__ void sqrtm_kernel(const float* __restrict__ cov,
                             const float* __restrict__ sf,
                             float* __restrict__ sout)
{
    __shared__ float b0[32][33], b1[32][33], b2[32][33], b3[32][33];
    __shared__ float sh_tr, sh_scale;
    const int bg = blockIdx.x;
    const int b = bg >> 2, g = bg & 3;
    const int tid = threadIdx.x;
    const int ei = (tid * 4) >> 5, ej0 = (tid * 4) & 31;
    const float* cp = cov + (size_t)bg * (Dn * Dn);
    const float* fs = sf + b * Cn + g * Dn;
    const float invM = 1.f / Mn;
    const float mi = fs[ei] * invM;
#pragma unroll
    for (int q = 0; q < 4; ++q)
        b0[ei][ej0 + q] = cp[ei * Dn + ej0 + q] * invM - mi * (fs[ej0 + q] * invM);
    __syncthreads();
    if (tid < 32) {
        float d = b0[tid][tid];
#pragma unroll
        for (int dd = 1; dd < 32; dd <<= 1) d += __shfl_xor(d, dd);
        if (tid == 0) { sh_tr = d; sh_scale = 0.5f * sqrtf(d); }
    }
    __syncthreads();
    const float invtr = 1.f / sh_tr;
#pragma unroll
    for (int q = 0; q < 4; ++q) {
        const float an = b0[ei][ej0 + q] * invtr;
        b0[ei][ej0 + q] = an;                                  // An
        b1[ei][ej0 + q] = ((ei == ej0 + q) ? 1.5f : 0.f) - 0.5f * an;  // ZY
    }
    __syncthreads();
    mm32(b0, b1, b2, ei, ej0);  // Y = An @ ZY
    float (*pY)[33] = b2;
    float (*pZ)[33] = b1;
    float (*pF1)[33] = b0;
    float (*pF2)[33] = b3;
#pragma unroll 1
    for (int it = 0; it < 3; ++it) {
        mm32(pZ, pY, pF1, ei, ej0);  // T = Z@Y
#pragma unroll
        for (int q = 0; q < 4; ++q)
            pF1[ei][ej0 + q] = ((ei == ej0 + q) ? 1.5f : 0.f) - 0.5f * pF1[ei][ej0 + q];
        __syncthreads();
        mm32(pY, pF1, pF2, ei, ej0);  // Ynew = Y@ZY
        mm32(pF1, pZ, pY, ei, ej0);   // Znew = ZY@Z (into old Y buffer)
        float (*oldZ)[33] = pZ;
        pZ = pY;
        pY = pF2;
        pF2 = oldZ;
    }
    mm32(pZ, pY, pF1, ei, ej0);  // T = Z@Y
#pragma unroll
    for (int q = 0; q < 4; ++q)
        pF1[ei][ej0 + q] = ((ei == ej0 + q) ? 3.f : 0.f) - pF1[ei][ej0 + q];
    __syncthreads();
    mm32(pY, pF1, pF2, ei, ej0);  // R = Y @ (3I - T)
    if (tid < 32) {
        float t = 0.f;
#pragma unroll
        for (int i = 0; i < 32; ++i) t += pF2[i][tid];
        sout[b * Cn + g * Dn + tid] = t * sh_scale * (1.f / Dn);
    }
}

// ---------------------------------------------------------------------------
// coef1: per-(b,c) affine coefficients for y = GN(v) and h1 = relu(BN(IN(y)))
// using analytic propagation of stats through the affine chain.
// Single block, 1024 threads.
// ---------------------------------------------------------------------------
__launch_bounds__(1024)
__global__ void coef1_kernel(const float* __restrict__ sf, const float* __restrict__ sf2,
                             const float* __restrict__ sfx, const float* __restrict__ sx,
                             const float* __restrict__ sx2, const float* __restrict__ s,
                             const float* __restrict__ gng, const float* __restrict__ gnb,
                             const float* __restrict__ bn1g, const float* __restrict__ bn1b,
                             float* __restrict__ Ay, float* __restrict__ By,
                             float* __restrict__ Ah, float* __restrict__ Bh)
{
    __shared__ float smv[Bn * Cn];   // per-(b,c) mean of v
    __shared__ float sm2[Bn * Cn];   // per-(b,c) E[v^2] then var_y
    __shared__ float smu[Bn * Gn], srs[Bn * Gn];
    __shared__ float sV[Cn];
    const int tid = threadIdx.x;
    const float invM = 1.f / Mn;
    for (int p = tid; p < Bn * Cn; p += 1024) {
        const float sv = s[p];
        smv[p] = fmaf(sv, sf[p], sx[p]) * invM;
        sm2[p] = (sv * sv * sf2[p] + 2.f * sv * sfx[p] + sx2[p]) * invM;
    }
    __syncthreads();
    if (tid < Bn * Gn) {
        const int base = tid * Dn;
        float mu = 0.f, e2 = 0.f;
        for (int c = 0; c < Dn; ++c) { mu += smv[base + c]; e2 += sm2[base + c]; }
        mu *= (1.f / Dn); e2 *= (1.f / Dn);
        smu[tid] = mu;
        srs[tid] = rsqrtf(e2 - mu * mu + GN_EPS);
    }
    __syncthreads();
    for (int p = tid; p < Bn * Cn; p += 1024) {
        const int c = p & (Cn - 1);
        const int bg = p >> 5;  // b*4 + (c>>5)
        const float ay = srs[bg] * gng[c];
        const float mv = smv[p];
        sm2[p] = ay * ay * (sm2[p] - mv * mv);  // var_y
    }
    __syncthreads();
    if (tid < Cn) {
        float V = 0.f;
        for (int b = 0; b < Bn; ++b) {
            const float vy = sm2[b * Cn + tid];
            V += vy / (vy + IN_EPS);
        }
        sV[tid] = V * (1.f / Bn);
    }
    __syncthreads();
    for (int p = tid; p < Bn * Cn; p += 1024) {
        const int c = p & (Cn - 1);
        const int bg = p >> 5;
        const float ay = srs[bg] * gng[c];
        const float mv = smv[p];
        const float by = gnb[c] - smu[bg] * ay;
        const float rsin = rsqrtf(sm2[p] + IN_EPS);
        const float ah = ay * rsin * rsqrtf(sV[c] + BN_EPS) * bn1g[c];
        const float bh = bn1b[c] - ah * mv;
        Ay[p] = ay; By[p] = by; Ah[p] = ah; Bh[p] = bh;
    }
}

// coef2: same trick for h3 = relu(BN(IN(h2))) from per-(b,c) sum/sumsq of h2
__launch_bounds__(1024)
__global__ void coef2_kernel(const float* __restrict__ sum1, const float* __restrict__ sum2,
                             const float* __restrict__ bn2g, const float* __restrict__ bn2b,
                             float* __restrict__ A2, float* __restrict__ B2)
{
    __shared__ float svar[Bn * Cn];
    __shared__ float sV[Cn];
    const int tid = threadIdx.x;
    const float invM = 1.f / Mn;
    for (int p = tid; p < Bn * Cn; p += 1024) {
        const float mu = sum1[p] * invM;
        svar[p] = sum2[p] * invM - mu * mu;
    }
    __syncthreads();
    if (tid < Cn) {
        float V = 0.f;
        for (int b = 0; b < Bn; ++b) {
            const float v = svar[b * Cn + tid];
            V += v / (v + IN_EPS);
        }
        sV[tid] = V * (1.f / Bn);
    }
    __syncthreads();
    for (int p = tid; p < Bn * Cn; p += 1024) {
        const int c = p & (Cn - 1);
        const float mu = sum1[p] * invM;
        const float a2 = rsqrtf(svar[p] + IN_EPS) * rsqrtf(sV[c] + BN_EPS) * bn2g[c];
        A2[p] = a2;
        B2[p] = bn2b[c] - a2 * mu;
    }
}

// ---------------------------------------------------------------------------
// Elementwise: v = s*feat + x ; y = Ay*v+By ; h1 = relu(Ah*v+Bh)
// ---------------------------------------------------------------------------
__launch_bounds__(256)
__global__ void ew_kernel(const float* __restrict__ feat, const float* __restrict__ x,
                          const float* __restrict__ s,
                          const float* __restrict__ Ay, const float* __restrict__ By,
                          const float* __restrict__ Ah, const float* __restrict__ Bh,
                          float* __restrict__ ybuf, float* __restrict__ h1buf)
{
    const int bc = blockIdx.x;
    const int tid = threadIdx.x;
    const float sv = s[bc], ay = Ay[bc], by = By[bc], ah = Ah[bc], bh = Bh[bc];
    const float4* f4 = (const float4*)(feat + (size_t)bc * Mn);
    const float4* x4 = (const float4*)(x + (size_t)bc * Mn);
    float4* y4 = (float4*)(ybuf + (size_t)bc * Mn);
    float4* h4 = (float4*)(h1buf + (size_t)bc * Mn);
    for (int p = tid; p < Mn / 4; p += 256) {
        const float4 f = f4[p], xx = x4[p];
        float4 yv, hv;
        float v;
        v = fmaf(sv, f.x, xx.x); yv.x = fmaf(ay, v, by); hv.x = fmaxf(fmaf(ah, v, bh), 0.f);
        v = fmaf(sv, f.y, xx.y); yv.y = fmaf(ay, v, by); hv.y = fmaxf(fmaf(ah, v, bh), 0.f);
        v = fmaf(sv, f.z, xx.z); yv.z = fmaf(ay, v, by); hv.z = fmaxf(fmaf(ah, v, bh), 0.f);
        v = fmaf(sv, f.w, xx.w); yv.w = fmaf(ay, v, by); hv.w = fmaxf(fmaf(ah, v, bh), 0.f);
        y4[p] = yv;
        h4[p] = hv;
    }
}

// ---------------------------------------------------------------------------
extern "C" void kernel_launch(void* const* d_in, const int* in_sizes, int n_in,
                              void* d_out, int out_size, void* d_ws, size_t ws_size,
                              hipStream_t stream)
{
    const float* x      = (const float*)d_in[0];
    const float* w_lin  = (const float*)d_in[1];
    const float* gn_g   = (const float*)d_in[2];
    const float* gn_b   = (const float*)d_in[3];
    const float* bn1g   = (const float*)d_in[4];
    const float* bn1b   = (const float*)d_in[5];
    const float* conv1w = (const float*)d_in[6];
    const float* conv1b = (const float*)d_in[7];
    const float* bn2g   = (const float*)d_in[8];
    const float* bn2b   = (const float*)d_in[9];
    const float* conv2w = (const float*)d_in[10];
    const float* conv2b = (const float*)d_in[11];
    float* out = (float*)d_out;

    float* ws = (float*)d_ws;
    size_t off = 0;
    float* feat = ws + off; off += (size_t)Bn * Cn * Mn;   // reused as h2 after ew
    float* ybuf = ws + off; off += (size_t)Bn * Cn * Mn;
    float* sarr = ws + off; off += Bn * Cn;
    float* Ay = ws + off; off += Bn * Cn;
    float* By = ws + off; off += Bn * Cn;
    float* Ah = ws + off; off += Bn * Cn;
    float* Bh = ws + off; off += Bn * Cn;
    float* A2 = ws + off; off += Bn * Cn;
    float* B2 = ws + off; off += Bn * Cn;
    // zero-initialized accumulator region (contiguous)
    float* zbase = ws + off;
    float* cov  = zbase;
    float* sf   = cov + Bn * Gn * Dn * Dn;
    float* sf2  = sf + Bn * Cn;
    float* sfx  = sf2 + Bn * Cn;
    float* sx   = sfx + Bn * Cn;
    float* sx2  = sx + Bn * Cn;
    float* sum1 = sx2 + Bn * Cn;
    float* sum2 = sum1 + Bn * Cn;
    const size_t zfloats = (size_t)Bn * Gn * Dn * Dn + 7 * Bn * Cn;

    hipMemsetAsync(zbase, 0, zfloats * sizeof(float), stream);

    const dim3 gemm_grid((Mn + 63) / 64, Cn / 64, Bn);
    const dim3 gemm_block(256);

    // 1) feat = w_linear @ x
    gemm_kernel<0><<<gemm_grid, gemm_block, 0, stream>>>(
        w_lin, x, feat, nullptr, nullptr, nullptr, nullptr, nullptr, nullptr);

    // 2) covariance raw moments + channel sums
    cov_kernel<<<dim3(CSPLIT, Gn, Bn), 256, 0, stream>>>(feat, x, cov, sf, sf2, sfx, sx, sx2);

    // 3) Newton-Schulz sqrtm -> s
    sqrtm_kernel<<<Bn * Gn, 256, 0, stream>>>(cov, sf, sarr);

    // 4) per-(b,c) affine coefficients for GN and first IN/BN/ReLU
    coef1_kernel<<<1, 1024, 0, stream>>>(sf, sf2, sfx, sx, sx2, sarr,
                                         gn_g, gn_b, bn1g, bn1b, Ay, By, Ah, Bh);

    // 5) y and h1 (h1 goes to d_out as scratch; fully rewritten later)
    ew_kernel<<<Bn * Cn, 256, 0, stream>>>(feat, x, sarr, Ay, By, Ah, Bh, ybuf, out);

    // 6) h2 = conv1_w @ h1 + conv1_b (into feat slot), accumulate stats
    gemm_kernel<1><<<gemm_grid, gemm_block, 0, stream>>>(
        conv1w, out, feat, conv1b, nullptr, nullptr, nullptr, sum1, sum2);

    // 7) second-stage affine coefficients
    coef2_kernel<<<1, 1024, 0, stream>>>(sum1, sum2, bn2g, bn2b, A2, B2);

    // 8) out = conv2_w @ relu(A2*h2+B2) + conv2_b + y
    gemm_kernel<2><<<gemm_grid, gemm_block, 0, stream>>>(
        conv2w, feat, out, conv2b, A2, B2, ybuf, nullptr, nullptr);
}

// Round 2
// 300.422 us; speedup vs baseline: 1.3691x; 1.3691x over previous
//
#include <hip/hip_runtime.h>

constexpr int Bn = 32;
constexpr int Cn = 128;
constexpr int Mn = 4000;
constexpr int Gn = 4;
constexpr int Dn = 32;   // C / G
constexpr float GN_EPS = 1e-5f;
constexpr float IN_EPS = 1e-3f;
constexpr float BN_EPS = 1e-5f;

// ---------------------------------------------------------------------------
// GEMM: out[b,o,m] = sum_c W[o,c] * f(in[b,c,m]) (+bias) (+yadd)
// MODE 0: plain (GEMM1)
// MODE 1: +bias, accumulate per-(b,o) sum/sumsq atomically (GEMM2)
// MODE 2: input transform relu(Atr*in+Btr), +bias, +yadd (GEMM3)
// ---------------------------------------------------------------------------
template <int MODE>
__launch_bounds__(256)
__global__ void gemm_kernel(const float* __restrict__ W,
                            const float* __restrict__ in,
                            float* __restrict__ out,
                            const float* __restrict__ bias,
                            const float* __restrict__ Atr,
                            const float* __restrict__ Btr,
                            const float* __restrict__ yadd,
                            float* __restrict__ sum1,
                            float* __restrict__ sum2)
{
    __shared__ float Wl[16][64];
    __shared__ float Il[16][64];
    const int b  = blockIdx.z;
    const int ob = blockIdx.y * 64;
    const int mb = blockIdx.x * 64;
    const int tid = threadIdx.x;
    const int ty = tid >> 4, tx = tid & 15;
    const float* inb = in + (size_t)b * Cn * Mn;

    const int lo  = tid >> 2;        // 0..63 W row in tile
    const int lkq = (tid & 3) * 4;   // 0,4,8,12
    const int lk  = tid >> 4;        // 0..15 input row in tile
    const int lmq = (tid & 15) * 4;  // 0..60

    float acc[4][4] = {};

    for (int kb = 0; kb < Cn; kb += 16) {
        float4 w4 = *(const float4*)(W + (size_t)(ob + lo) * Cn + kb + lkq);
        float4 v4;
        const int gm = mb + lmq;
        if (gm < Mn) v4 = *(const float4*)(inb + (size_t)(kb + lk) * Mn + gm);
        else         v4 = make_float4(0.f, 0.f, 0.f, 0.f);
        if (MODE == 2) {
            const float a  = Atr[b * Cn + kb + lk];
            const float bb = Btr[b * Cn + kb + lk];
            v4.x = fmaxf(fmaf(a, v4.x, bb), 0.f);
            v4.y = fmaxf(fmaf(a, v4.y, bb), 0.f);
            v4.z = fmaxf(fmaf(a, v4.z, bb), 0.f);
            v4.w = fmaxf(fmaf(a, v4.w, bb), 0.f);
        }
        Wl[lkq + 0][lo] = w4.x;
        Wl[lkq + 1][lo] = w4.y;
        Wl[lkq + 2][lo] = w4.z;
        Wl[lkq + 3][lo] = w4.w;
        *(float4*)&Il[lk][lmq] = v4;
        __syncthreads();
#pragma unroll
        for (int k = 0; k < 16; ++k) {
            const float4 a4 = *(const float4*)&Wl[k][ty * 4];
            const float4 b4 = *(const float4*)&Il[k][tx * 4];
            const float av[4] = {a4.x, a4.y, a4.z, a4.w};
            const float bv[4] = {b4.x, b4.y, b4.z, b4.w};
#pragma unroll
            for (int i = 0; i < 4; ++i)
#pragma unroll
                for (int j = 0; j < 4; ++j)
                    acc[i][j] = fmaf(av[i], bv[j], acc[i][j]);
        }
        __syncthreads();
    }

    float ssum[4] = {0.f, 0.f, 0.f, 0.f}, sqsum[4] = {0.f, 0.f, 0.f, 0.f};
    const int m0 = mb + tx * 4;
#pragma unroll
    for (int i = 0; i < 4; ++i) {
        const int o = ob + ty * 4 + i;
        const float bv = (MODE >= 1) ? bias[o] : 0.f;
        const size_t base = (size_t)b * Cn * Mn + (size_t)o * Mn + m0;
        if (m0 + 3 < Mn) {
            float4 r;
            r.x = acc[i][0] + bv;
            r.y = acc[i][1] + bv;
            r.z = acc[i][2] + bv;
            r.w = acc[i][3] + bv;
            if (MODE == 2) {
                const float4 y4 = *(const float4*)(yadd + base);
                r.x += y4.x; r.y += y4.y; r.z += y4.z; r.w += y4.w;
            }
            *(float4*)(out + base) = r;
            if (MODE == 1) {
                ssum[i]  = r.x + r.y + r.z + r.w;
                sqsum[i] = r.x * r.x + r.y * r.y + r.z * r.z + r.w * r.w;
            }
        } else {
#pragma unroll
            for (int j = 0; j < 4; ++j) {
                if (m0 + j < Mn) {
                    float r = acc[i][j] + bv;
                    if (MODE == 2) r += yadd[base + j];
                    out[base + j] = r;
                    if (MODE == 1) { ssum[i] += r; sqsum[i] += r * r; }
                }
            }
        }
    }
    if (MODE == 1) {
#pragma unroll
        for (int i = 0; i < 4; ++i) {
            float s = ssum[i], q = sqsum[i];
#pragma unroll
            for (int d = 1; d < 16; d <<= 1) {
                s += __shfl_xor(s, d);
                q += __shfl_xor(q, d);
            }
            if (tx == 0) {
                const int o = ob + ty * 4 + i;
                atomicAdd(&sum1[b * Cn + o], s);
                atomicAdd(&sum2[b * Cn + o], q);
            }
        }
    }
}

// ---------------------------------------------------------------------------
// Covariance (raw second moments) + per-channel sums of f, f^2, f*x, x, x^2.
// m-major LDS tile fl[MT][33]: all 64 lanes of a wave read the SAME m
// (8 distinct b128 addresses x 8-lane broadcast = conflict-free).
// grid: (MSPLIT, G, B), 256 threads.
// ---------------------------------------------------------------------------
constexpr int MSPLIT = 8;
constexpr int MSEG = Mn / MSPLIT;  // 500
constexpr int MT = 64;

__launch_bounds__(256)
__global__ void cov_kernel(const float* __restrict__ feat, const float* __restrict__ x,
                           float* __restrict__ cov,
                           float* __restrict__ sf, float* __restrict__ sf2,
                           float* __restrict__ sfx, float* __restrict__ sx,
                           float* __restrict__ sx2)
{
    __shared__ float fl[MT][33];       // m-major, +1 pad
    __shared__ float red[4][64 * 17];  // cross-wave acc reduction, padded
    const int sp = blockIdx.x, g = blockIdx.y, b = blockIdx.z;
    const int tid = threadIdx.x;
    const int r = tid >> 3;            // 0..31: channel row this thread loads
    const int q = tid & 7;             // m-octet within tile
    const size_t rowbase = ((size_t)b * Cn + g * Dn + r) * Mn + (size_t)sp * MSEG;
    const float* fr = feat + rowbase;
    const float* xr = x + rowbase;

    const int wv = tid >> 6, l = tid & 63;
    const int i4 = (l & 7) * 4;        // output rows i4..i4+3
    const int j4 = (l >> 3) * 4;       // output cols j4..j4+3

    float acc[4][4] = {};
    float cf = 0.f, cf2 = 0.f, cfx = 0.f, cx = 0.f, cx2 = 0.f;

    for (int t0 = 0; t0 < MSEG; t0 += MT) {
        const int lim = MSEG - t0;     // >= MT except last tile (52)
        const int mb0 = q * 8;
        if (lim >= MT) {
            const float4 fa = *(const float4*)(fr + t0 + mb0);
            const float4 fb = *(const float4*)(fr + t0 + mb0 + 4);
            const float4 xa = *(const float4*)(xr + t0 + mb0);
            const float4 xb = *(const float4*)(xr + t0 + mb0 + 4);
            cf += fa.x + fa.y + fa.z + fa.w + fb.x + fb.y + fb.z + fb.w;
            cf2 = fmaf(fa.x, fa.x, fmaf(fa.y, fa.y, fmaf(fa.z, fa.z, fmaf(fa.w, fa.w, cf2))));
            cf2 = fmaf(fb.x, fb.x, fmaf(fb.y, fb.y, fmaf(fb.z, fb.z, fmaf(fb.w, fb.w, cf2))));
            cfx = fmaf(fa.x, xa.x, fmaf(fa.y, xa.y, fmaf(fa.z, xa.z, fmaf(fa.w, xa.w, cfx))));
            cfx = fmaf(fb.x, xb.x, fmaf(fb.y, xb.y, fmaf(fb.z, xb.z, fmaf(fb.w, xb.w, cfx))));
            cx += xa.x + xa.y + xa.z + xa.w + xb.x + xb.y + xb.z + xb.w;
            cx2 = fmaf(xa.x, xa.x, fmaf(xa.y, xa.y, fmaf(xa.z, xa.z, fmaf(xa.w, xa.w, cx2))));
            cx2 = fmaf(xb.x, xb.x, fmaf(xb.y, xb.y, fmaf(xb.z, xb.z, fmaf(xb.w, xb.w, cx2))));
            fl[mb0 + 0][r] = fa.x; fl[mb0 + 1][r] = fa.y;
            fl[mb0 + 2][r] = fa.z; fl[mb0 + 3][r] = fa.w;
            fl[mb0 + 4][r] = fb.x; fl[mb0 + 5][r] = fb.y;
            fl[mb0 + 6][r] = fb.z; fl[mb0 + 7][r] = fb.w;
        } else {
#pragma unroll
            for (int k = 0; k < 8; ++k) {
                const int ml = mb0 + k;
                float fv = 0.f;
                if (ml < lim) {
                    fv = fr[t0 + ml];
                    const float xv = xr[t0 + ml];
                    cf += fv; cf2 = fmaf(fv, fv, cf2); cfx = fmaf(fv, xv, cfx);
                    cx += xv; cx2 = fmaf(xv, xv, cx2);
                }
                fl[ml][r] = fv;
            }
        }
        __syncthreads();
#pragma unroll
        for (int mm = 0; mm < 16; ++mm) {
            const int m = wv * 16 + mm;
            const float4 fi = *(const float4*)&fl[m][i4];
            const float4 fj = *(const float4*)&fl[m][j4];
            const float av[4] = {fi.x, fi.y, fi.z, fi.w};
            const float bv[4] = {fj.x, fj.y, fj.z, fj.w};
#pragma unroll
            for (int i = 0; i < 4; ++i)
#pragma unroll
                for (int j = 0; j < 4; ++j)
                    acc[i][j] = fmaf(av[i], bv[j], acc[i][j]);
        }
        __syncthreads();
    }

    // cross-wave reduction of the 32x32 accumulators, then 1 atomic/entry
#pragma unroll
    for (int i = 0; i < 4; ++i)
#pragma unroll
        for (int j = 0; j < 4; ++j)
            red[wv][l * 17 + i * 4 + j] = acc[i][j];
    __syncthreads();
    float* cvb = cov + (size_t)(b * Gn + g) * (Dn * Dn);
    for (int e = tid; e < 1024; e += 256) {
        const int ll = e >> 4, idx = e & 15;
        const int a = ll * 17 + idx;
        const float v = red[0][a] + red[1][a] + red[2][a] + red[3][a];
        const int gi = (ll & 7) * 4 + (idx >> 2);
        const int gj = (ll >> 3) * 4 + (idx & 3);
        atomicAdd(&cvb[gi * Dn + gj], v);
    }

    // channel sums: reduce over the 8-lane m-octet group (same r)
#pragma unroll
    for (int d = 1; d < 8; d <<= 1) {
        cf  += __shfl_xor(cf, d);
        cf2 += __shfl_xor(cf2, d);
        cfx += __shfl_xor(cfx, d);
        cx  += __shfl_xor(cx, d);
        cx2 += __shfl_xor(cx2, d);
    }
    if (q == 0) {
        const int ch = b * Cn + g * Dn + r;
        atomicAdd(&sf[ch], cf);
        atomicAdd(&sf2[ch], cf2);
        atomicAdd(&sfx[ch], cfx);
        atomicAdd(&sx[ch], cx);
        atomicAdd(&sx2[ch], cx2);
    }
}

// ---------------------------------------------------------------------------
// Newton-Schulz sqrtm per (b,g) 32x32 + row-mean -> s[b,c]
// ---------------------------------------------------------------------------
__device__ __forceinline__ void mm32(float (*A)[33], float (*Bm)[33],
                                     float (*O)[33], int ei, int ej0)
{
    float a0 = 0.f, a1 = 0.f, a2 = 0.f, a3 = 0.f;
#pragma unroll
    for (int k = 0; k < 32; ++k) {
        const float a = A[ei][k];
        a0 = fmaf(a, Bm[k][ej0 + 0], a0);
        a1 = fmaf(a, Bm[k][ej0 + 1], a1);
        a2 = fmaf(a, Bm[k][ej0 + 2], a2);
        a3 = fmaf(a, Bm[k][ej0 + 3], a3);
    }
    O[ei][ej0 + 0] = a0;
    O[ei][ej0 + 1] = a1;
    O[ei][ej0 + 2] = a2;
    O[ei][ej0 + 3] = a3;
    __syncthreads();
}

__launch_bounds__(256)
__global__ void sqrtm_kernel(const float* __restrict__ cov,
                             const float* __restrict__ sf,
                             float* __restrict__ sout)
{
    __shared__ float b0[32][33], b1[32][33], b2[32][33], b3[32][33];
    __shared__ float sh_tr, sh_scale;
    const int bg = blockIdx.x;
    const int b = bg >> 2, g = bg & 3;
    const int tid = threadIdx.x;
    const int ei = (tid * 4) >> 5, ej0 = (tid * 4) & 31;
    const float* cp = cov + (size_t)bg * (Dn * Dn);
    const float* fs = sf + b * Cn + g * Dn;
    const float invM = 1.f / Mn;
    const float mi = fs[ei] * invM;
#pragma unroll
    for (int q = 0; q < 4; ++q)
        b0[ei][ej0 + q] = cp[ei * Dn + ej0 + q] * invM - mi * (fs[ej0 + q] * invM);
    __syncthreads();
    if (tid < 32) {
        float d = b0[tid][tid];
#pragma unroll
        for (int dd = 1; dd < 32; dd <<= 1) d += __shfl_xor(d, dd);
        if (tid == 0) { sh_tr = d; sh_scale = 0.5f * sqrtf(d); }
    }
    __syncthreads();
    const float invtr = 1.f / sh_tr;
#pragma unroll
    for (int q = 0; q < 4; ++q) {
        const float an = b0[ei][ej0 + q] * invtr;
        b0[ei][ej0 + q] = an;                                  // An
        b1[ei][ej0 + q] = ((ei == ej0 + q) ? 1.5f : 0.f) - 0.5f * an;  // ZY
    }
    __syncthreads();
    mm32(b0, b1, b2, ei, ej0);  // Y = An @ ZY
    float (*pY)[33] = b2;
    float (*pZ)[33] = b1;
    float (*pF1)[33] = b0;
    float (*pF2)[33] = b3;
#pragma unroll 1
    for (int it = 0; it < 3; ++it) {
        mm32(pZ, pY, pF1, ei, ej0);  // T = Z@Y
#pragma unroll
        for (int q = 0; q < 4; ++q)
            pF1[ei][ej0 + q] = ((ei == ej0 + q) ? 1.5f : 0.f) - 0.5f * pF1[ei][ej0 + q];
        __syncthreads();
        mm32(pY, pF1, pF2, ei, ej0);  // Ynew = Y@ZY
        mm32(pF1, pZ, pY, ei, ej0);   // Znew = ZY@Z (into old Y buffer)
        float (*oldZ)[33] = pZ;
        pZ = pY;
        pY = pF2;
        pF2 = oldZ;
    }
    mm32(pZ, pY, pF1, ei, ej0);  // T = Z@Y
#pragma unroll
    for (int q = 0; q < 4; ++q)
        pF1[ei][ej0 + q] = ((ei == ej0 + q) ? 3.f : 0.f) - pF1[ei][ej0 + q];
    __syncthreads();
    mm32(pY, pF1, pF2, ei, ej0);  // R = Y @ (3I - T)
    if (tid < 32) {
        float t = 0.f;
#pragma unroll
        for (int i = 0; i < 32; ++i) t += pF2[i][tid];
        sout[b * Cn + g * Dn + tid] = t * sh_scale * (1.f / Dn);
    }
}

// ---------------------------------------------------------------------------
// coef1: per-(b,c) affine coefficients for y = GN(v) and h1 = relu(BN(IN(y)))
// ---------------------------------------------------------------------------
__launch_bounds__(1024)
__global__ void coef1_kernel(const float* __restrict__ sf, const float* __restrict__ sf2,
                             const float* __restrict__ sfx, const float* __restrict__ sx,
                             const float* __restrict__ sx2, const float* __restrict__ s,
                             const float* __restrict__ gng, const float* __restrict__ gnb,
                             const float* __restrict__ bn1g, const float* __restrict__ bn1b,
                             float* __restrict__ Ay, float* __restrict__ By,
                             float* __restrict__ Ah, float* __restrict__ Bh)
{
    __shared__ float smv[Bn * Cn];   // per-(b,c) mean of v
    __shared__ float sm2[Bn * Cn];   // per-(b,c) E[v^2] then var_y
    __shared__ float smu[Bn * Gn], srs[Bn * Gn];
    __shared__ float sV[Cn];
    const int tid = threadIdx.x;
    const float invM = 1.f / Mn;
    for (int p = tid; p < Bn * Cn; p += 1024) {
        const float sv = s[p];
        smv[p] = fmaf(sv, sf[p], sx[p]) * invM;
        sm2[p] = (sv * sv * sf2[p] + 2.f * sv * sfx[p] + sx2[p]) * invM;
    }
    __syncthreads();
    if (tid < Bn * Gn) {
        const int base = tid * Dn;
        float mu = 0.f, e2 = 0.f;
        for (int c = 0; c < Dn; ++c) { mu += smv[base + c]; e2 += sm2[base + c]; }
        mu *= (1.f / Dn); e2 *= (1.f / Dn);
        smu[tid] = mu;
        srs[tid] = rsqrtf(e2 - mu * mu + GN_EPS);
    }
    __syncthreads();
    for (int p = tid; p < Bn * Cn; p += 1024) {
        const int c = p & (Cn - 1);
        const int bg = p >> 5;  // b*4 + (c>>5)
        const float ay = srs[bg] * gng[c];
        const float mv = smv[p];
        sm2[p] = ay * ay * (sm2[p] - mv * mv);  // var_y
    }
    __syncthreads();
    if (tid < Cn) {
        float V = 0.f;
        for (int b = 0; b < Bn; ++b) {
            const float vy = sm2[b * Cn + tid];
            V += vy / (vy + IN_EPS);
        }
        sV[tid] = V * (1.f / Bn);
    }
    __syncthreads();
    for (int p = tid; p < Bn * Cn; p += 1024) {
        const int c = p & (Cn - 1);
        const int bg = p >> 5;
        const float ay = srs[bg] * gng[c];
        const float mv = smv[p];
        const float by = gnb[c] - smu[bg] * ay;
        const float rsin = rsqrtf(sm2[p] + IN_EPS);
        const float ah = ay * rsin * rsqrtf(sV[c] + BN_EPS) * bn1g[c];
        const float bh = bn1b[c] - ah * mv;
        Ay[p] = ay; By[p] = by; Ah[p] = ah; Bh[p] = bh;
    }
}

// coef2: same trick for h3 = relu(BN(IN(h2))) from per-(b,c) sum/sumsq of h2
__launch_bounds__(1024)
__global__ void coef2_kernel(const float* __restrict__ sum1, const float* __restrict__ sum2,
                             const float* __restrict__ bn2g, const float* __restrict__ bn2b,
                             float* __restrict__ A2, float* __restrict__ B2)
{
    __shared__ float svar[Bn * Cn];
    __shared__ float sV[Cn];
    const int tid = threadIdx.x;
    const float invM = 1.f / Mn;
    for (int p = tid; p < Bn * Cn; p += 1024) {
        const float mu = sum1[p] * invM;
        svar[p] = sum2[p] * invM - mu * mu;
    }
    __syncthreads();
    if (tid < Cn) {
        float V = 0.f;
        for (int b = 0; b < Bn; ++b) {
            const float v = svar[b * Cn + tid];
            V += v / (v + IN_EPS);
        }
        sV[tid] = V * (1.f / Bn);
    }
    __syncthreads();
    for (int p = tid; p < Bn * Cn; p += 1024) {
        const int c = p & (Cn - 1);
        const float mu = sum1[p] * invM;
        const float a2 = rsqrtf(svar[p] + IN_EPS) * rsqrtf(sV[c] + BN_EPS) * bn2g[c];
        A2[p] = a2;
        B2[p] = bn2b[c] - a2 * mu;
    }
}

// ---------------------------------------------------------------------------
// Elementwise: v = s*feat + x ; y = Ay*v+By ; h1 = relu(Ah*v+Bh)
// ---------------------------------------------------------------------------
__launch_bounds__(256)
__global__ void ew_kernel(const float* __restrict__ feat, const float* __restrict__ x,
                          const float* __restrict__ s,
                          const float* __restrict__ Ay, const float* __restrict__ By,
                          const float* __restrict__ Ah, const float* __restrict__ Bh,
                          float* __restrict__ ybuf, float* __restrict__ h1buf)
{
    const int bc = blockIdx.x;
    const int tid = threadIdx.x;
    const float sv = s[bc], ay = Ay[bc], by = By[bc], ah = Ah[bc], bh = Bh[bc];
    const float4* f4 = (const float4*)(feat + (size_t)bc * Mn);
    const float4* x4 = (const float4*)(x + (size_t)bc * Mn);
    float4* y4 = (float4*)(ybuf + (size_t)bc * Mn);
    float4* h4 = (float4*)(h1buf + (size_t)bc * Mn);
    for (int p = tid; p < Mn / 4; p += 256) {
        const float4 f = f4[p], xx = x4[p];
        float4 yv, hv;
        float v;
        v = fmaf(sv, f.x, xx.x); yv.x = fmaf(ay, v, by); hv.x = fmaxf(fmaf(ah, v, bh), 0.f);
        v = fmaf(sv, f.y, xx.y); yv.y = fmaf(ay, v, by); hv.y = fmaxf(fmaf(ah, v, bh), 0.f);
        v = fmaf(sv, f.z, xx.z); yv.z = fmaf(ay, v, by); hv.z = fmaxf(fmaf(ah, v, bh), 0.f);
        v = fmaf(sv, f.w, xx.w); yv.w = fmaf(ay, v, by); hv.w = fmaxf(fmaf(ah, v, bh), 0.f);
        y4[p] = yv;
        h4[p] = hv;
    }
}

// ---------------------------------------------------------------------------
extern "C" void kernel_launch(void* const* d_in, const int* in_sizes, int n_in,
                              void* d_out, int out_size, void* d_ws, size_t ws_size,
                              hipStream_t stream)
{
    const float* x      = (const float*)d_in[0];
    const float* w_lin  = (const float*)d_in[1];
    const float* gn_g   = (const float*)d_in[2];
    const float* gn_b   = (const float*)d_in[3];
    const float* bn1g   = (const float*)d_in[4];
    const float* bn1b   = (const float*)d_in[5];
    const float* conv1w = (const float*)d_in[6];
    const float* conv1b = (const float*)d_in[7];
    const float* bn2g   = (const float*)d_in[8];
    const float* bn2b   = (const float*)d_in[9];
    const float* conv2w = (const float*)d_in[10];
    const float* conv2b = (const float*)d_in[11];
    float* out = (float*)d_out;

    float* ws = (float*)d_ws;
    size_t off = 0;
    float* feat = ws + off; off += (size_t)Bn * Cn * Mn;   // reused as h2 after ew
    float* ybuf = ws + off; off += (size_t)Bn * Cn * Mn;
    float* sarr = ws + off; off += Bn * Cn;
    float* Ay = ws + off; off += Bn * Cn;
    float* By = ws + off; off += Bn * Cn;
    float* Ah = ws + off; off += Bn * Cn;
    float* Bh = ws + off; off += Bn * Cn;
    float* A2 = ws + off; off += Bn * Cn;
    float* B2 = ws + off; off += Bn * Cn;
    // zero-initialized accumulator region (contiguous)
    float* zbase = ws + off;
    float* cov  = zbase;
    float* sf   = cov + Bn * Gn * Dn * Dn;
    float* sf2  = sf + Bn * Cn;
    float* sfx  = sf2 + Bn * Cn;
    float* sx   = sfx + Bn * Cn;
    float* sx2  = sx + Bn * Cn;
    float* sum1 = sx2 + Bn * Cn;
    float* sum2 = sum1 + Bn * Cn;
    const size_t zfloats = (size_t)Bn * Gn * Dn * Dn + 7 * Bn * Cn;

    hipMemsetAsync(zbase, 0, zfloats * sizeof(float), stream);

    const dim3 gemm_grid((Mn + 63) / 64, Cn / 64, Bn);
    const dim3 gemm_block(256);

    // 1) feat = w_linear @ x
    gemm_kernel<0><<<gemm_grid, gemm_block, 0, stream>>>(
        w_lin, x, feat, nullptr, nullptr, nullptr, nullptr, nullptr, nullptr);

    // 2) covariance raw moments + channel sums
    cov_kernel<<<dim3(MSPLIT, Gn, Bn), 256, 0, stream>>>(feat, x, cov, sf, sf2, sfx, sx, sx2);

    // 3) Newton-Schulz sqrtm -> s
    sqrtm_kernel<<<Bn * Gn, 256, 0, stream>>>(cov, sf, sarr);

    // 4) per-(b,c) affine coefficients for GN and first IN/BN/ReLU
    coef1_kernel<<<1, 1024, 0, stream>>>(sf, sf2, sfx, sx, sx2, sarr,
                                         gn_g, gn_b, bn1g, bn1b, Ay, By, Ah, Bh);

    // 5) y and h1 (h1 goes to d_out as scratch; fully rewritten later)
    ew_kernel<<<Bn * Cn, 256, 0, stream>>>(feat, x, sarr, Ay, By, Ah, Bh, ybuf, out);

    // 6) h2 = conv1_w @ h1 + conv1_b (into feat slot), accumulate stats
    gemm_kernel<1><<<gemm_grid, gemm_block, 0, stream>>>(
        conv1w, out, feat, conv1b, nullptr, nullptr, nullptr, sum1, sum2);

    // 7) second-stage affine coefficients
    coef2_kernel<<<1, 1024, 0, stream>>>(sum1, sum2, bn2g, bn2b, A2, B2);

    // 8) out = conv2_w @ relu(A2*h2+B2) + conv2_b + y
    gemm_kernel<2><<<gemm_grid, gemm_block, 0, stream>>>(
        conv2w, feat, out, conv2b, A2, B2, ybuf, nullptr, nullptr);
}

// Round 3
// 292.185 us; speedup vs baseline: 1.4077x; 1.0282x over previous
//
#include <hip/hip_runtime.h>

constexpr int Bn = 32;
constexpr int Cn = 128;
constexpr int Mn = 4000;
constexpr int Gn = 4;
constexpr int Dn = 32;   // C / G
constexpr float GN_EPS = 1e-5f;
constexpr float IN_EPS = 1e-3f;
constexpr float BN_EPS = 1e-5f;

typedef __attribute__((ext_vector_type(8))) short bf16x8;
typedef __attribute__((ext_vector_type(4))) float f32x4;

__device__ __forceinline__ float bf2f(ushort u) {
    union { unsigned int u; float f; } v;
    v.u = ((unsigned int)u) << 16;
    return v.f;
}
__device__ __forceinline__ ushort f2bf(float f) {
    union { float f; unsigned int u; } v;
    v.f = f;
    unsigned int r = v.u + 0x7FFFu + ((v.u >> 16) & 1u);
    return (ushort)(r >> 16);
}

// ---------------------------------------------------------------------------
// prep_w: fp32 W[128][128] -> bf16 (row-major [o][c])
// ---------------------------------------------------------------------------
__global__ void prep_w(const float* __restrict__ w, ushort* __restrict__ wb) {
    const int i = blockIdx.x * 256 + threadIdx.x;   // 16384 total
    wb[i] = f2bf(w[i]);
}

// ---------------------------------------------------------------------------
// prep_xt: x [b][c][m] fp32 -> xt [b][m][c] bf16 (32x32 LDS tile transpose)
// grid (Mn/32, Cn/32, Bn)
// ---------------------------------------------------------------------------
__launch_bounds__(256)
__global__ void prep_xt(const float* __restrict__ x, ushort* __restrict__ xt) {
    __shared__ float tl[32 * 33];
    const int mb = blockIdx.x * 32, cb = blockIdx.y * 32, b = blockIdx.z;
    const int tid = threadIdx.x;
    const int mi = tid & 31;
#pragma unroll
    for (int p = 0; p < 4; ++p) {
        const int ci = (tid >> 5) + 8 * p;
        tl[ci * 33 + mi] = x[((size_t)b * Cn + cb + ci) * Mn + mb + mi];
    }
    __syncthreads();
#pragma unroll
    for (int p = 0; p < 4; ++p) {
        const int mi2 = (tid >> 5) + 8 * p;
        const int ci2 = tid & 31;
        xt[((size_t)b * Mn + mb + mi2) * Cn + cb + ci2] = f2bf(tl[ci2 * 33 + mi2]);
    }
}

// ---------------------------------------------------------------------------
// MFMA GEMM: D[b][m][o] = sum_c T(src[b][m][c]) * W[o][c]
// MODE 0: T = identity (src=xt)            -> featt bf16 [b][m][o]
// MODE 1: T = relu(tA*(s*f+x)+tB)          -> h2t bf16, +bias, +sum1/sum2
// MODE 2: T = relu(tA*h2+tB)               -> out fp32 [b][o][m], +bias,
//             + y where y = Ay*(s*featt+xt)+By at output coords
// block: 256 thr = 4 waves; block tile 128m x 128o; wave tile 32m x 128o
// grid: (ceil(Mn/128), Bn)
// ---------------------------------------------------------------------------
template <int MODE>
__launch_bounds__(256)
__global__ void mgemm_kernel(const ushort* __restrict__ Wb,
                             const ushort* __restrict__ src,
                             const ushort* __restrict__ xsrc,
                             ushort* __restrict__ dst_bf,
                             float* __restrict__ dst_f32,
                             const float* __restrict__ bias,
                             const float* __restrict__ sarr,
                             const float* __restrict__ tA,
                             const float* __restrict__ tB,
                             const float* __restrict__ Ayc,
                             const float* __restrict__ Byc,
                             const ushort* __restrict__ featt,
                             const ushort* __restrict__ xt2,
                             float* __restrict__ sum1,
                             float* __restrict__ sum2)
{
    __shared__ ushort Wl[128 * 136];
    const int b = blockIdx.y;
    const int mb = blockIdx.x * 128;
    const int tid = threadIdx.x;
    const int wv = tid >> 6, l = tid & 63;
    const int li = l & 15, lg = l >> 4;

    // stage W (bf16 [128][128]) -> LDS padded [128][136]
#pragma unroll
    for (int p = 0; p < 8; ++p) {
        const int u = tid + 256 * p;          // uint4 index, 2048 total
        const int o = u >> 4, c8 = (u & 15) * 8;
        *(bf16x8*)&Wl[o * 136 + c8] = *(const bf16x8*)(Wb + o * 128 + c8);
    }
    __syncthreads();

    f32x4 acc[2][8];
#pragma unroll
    for (int t = 0; t < 2; ++t)
#pragma unroll
        for (int j = 0; j < 8; ++j)
#pragma unroll
            for (int r = 0; r < 4; ++r) acc[t][j][r] = 0.f;

#pragma unroll
    for (int kb = 0; kb < 4; ++kb) {
        const int cl = kb * 32 + 8 * lg;      // lane's c-base (8 consecutive c)

        float tAv[8], tBv[8], svv[8];
        if (MODE >= 1) {
            const float4 a0 = *(const float4*)(tA + b * Cn + cl);
            const float4 a1 = *(const float4*)(tA + b * Cn + cl + 4);
            const float4 b0 = *(const float4*)(tB + b * Cn + cl);
            const float4 b1 = *(const float4*)(tB + b * Cn + cl + 4);
            tAv[0]=a0.x; tAv[1]=a0.y; tAv[2]=a0.z; tAv[3]=a0.w;
            tAv[4]=a1.x; tAv[5]=a1.y; tAv[6]=a1.z; tAv[7]=a1.w;
            tBv[0]=b0.x; tBv[1]=b0.y; tBv[2]=b0.z; tBv[3]=b0.w;
            tBv[4]=b1.x; tBv[5]=b1.y; tBv[6]=b1.z; tBv[7]=b1.w;
            if (MODE == 1) {
                const float4 s0 = *(const float4*)(sarr + b * Cn + cl);
                const float4 s1 = *(const float4*)(sarr + b * Cn + cl + 4);
                svv[0]=s0.x; svv[1]=s0.y; svv[2]=s0.z; svv[3]=s0.w;
                svv[4]=s1.x; svv[5]=s1.y; svv[6]=s1.z; svv[7]=s1.w;
            }
        }

        bf16x8 af[2];
#pragma unroll
        for (int t = 0; t < 2; ++t) {
            const int m = mb + wv * 32 + t * 16 + li;
            if (m < Mn) {
                const size_t q = ((size_t)b * Mn + m) * Cn + cl;
                if (MODE == 0) {
                    af[t] = *(const bf16x8*)(src + q);
                } else if (MODE == 1) {
                    const bf16x8 f8 = *(const bf16x8*)(src + q);
                    const bf16x8 x8 = *(const bf16x8*)(xsrc + q);
#pragma unroll
                    for (int e = 0; e < 8; ++e) {
                        const float vv = fmaf(svv[e], bf2f((ushort)f8[e]), bf2f((ushort)x8[e]));
                        af[t][e] = (short)f2bf(fmaxf(fmaf(tAv[e], vv, tBv[e]), 0.f));
                    }
                } else {
                    const bf16x8 f8 = *(const bf16x8*)(src + q);
#pragma unroll
                    for (int e = 0; e < 8; ++e) {
                        const float fv = bf2f((ushort)f8[e]);
                        af[t][e] = (short)f2bf(fmaxf(fmaf(tAv[e], fv, tBv[e]), 0.f));
                    }
                }
            } else {
#pragma unroll
                for (int e = 0; e < 8; ++e) af[t][e] = 0;
            }
        }

#pragma unroll
        for (int j = 0; j < 8; ++j) {
            const bf16x8 bj = *(const bf16x8*)&Wl[(j * 16 + li) * 136 + cl];
            acc[0][j] = __builtin_amdgcn_mfma_f32_16x16x32_bf16(af[0], bj, acc[0][j], 0, 0, 0);
            acc[1][j] = __builtin_amdgcn_mfma_f32_16x16x32_bf16(af[1], bj, acc[1][j], 0, 0, 0);
        }
    }

    // ---------------- epilogues ----------------
    if (MODE == 0) {
#pragma unroll
        for (int j = 0; j < 8; ++j) {
            const int o = j * 16 + li;
#pragma unroll
            for (int t = 0; t < 2; ++t)
#pragma unroll
                for (int r = 0; r < 4; ++r) {
                    const int m = mb + wv * 32 + t * 16 + lg * 4 + r;
                    if (m < Mn)
                        dst_bf[((size_t)b * Mn + m) * Cn + o] = f2bf(acc[t][j][r]);
                }
        }
    } else if (MODE == 1) {
#pragma unroll
        for (int j = 0; j < 8; ++j) {
            const int o = j * 16 + li;
            const float bv = bias[o];
            float s1 = 0.f, s2 = 0.f;
#pragma unroll
            for (int t = 0; t < 2; ++t)
#pragma unroll
                for (int r = 0; r < 4; ++r) {
                    const int m = mb + wv * 32 + t * 16 + lg * 4 + r;
                    if (m < Mn) {
                        const float v = acc[t][j][r] + bv;
                        dst_bf[((size_t)b * Mn + m) * Cn + o] = f2bf(v);
                        s1 += v;
                        s2 = fmaf(v, v, s2);
                    }
                }
            s1 += __shfl_xor(s1, 16); s1 += __shfl_xor(s1, 32);
            s2 += __shfl_xor(s2, 16); s2 += __shfl_xor(s2, 32);
            if (lg == 0) {
                atomicAdd(&sum1[b * Cn + o], s1);
                atomicAdd(&sum2[b * Cn + o], s2);
            }
        }
    } else {
        // MODE 2: add bias + y, transpose via LDS (aliases Wl), store [o][m] f32
        float* TR = (float*)&Wl[0];   // needs 64*132*4 = 33792 B <= 34816 B
        __syncthreads();              // all waves done reading Wl
#pragma unroll
        for (int h = 0; h < 2; ++h) {
#pragma unroll
            for (int jj = 0; jj < 4; ++jj) {
                const int j = h * 4 + jj;
                const int o = j * 16 + li;
                const float bv = bias[o];
                const float sv = sarr[b * Cn + o];
                const float ayv = Ayc[b * Cn + o];
                const float byv = Byc[b * Cn + o];
#pragma unroll
                for (int t = 0; t < 2; ++t)
#pragma unroll
                    for (int r = 0; r < 4; ++r) {
                        const int ml = wv * 32 + t * 16 + lg * 4 + r;
                        const int m = mb + ml;
                        float v = acc[t][j][r] + bv;
                        if (m < Mn) {
                            const size_t q = ((size_t)b * Mn + m) * Cn + o;
                            const float fv = bf2f(featt[q]);
                            const float xv = bf2f(xt2[q]);
                            v += fmaf(ayv, fmaf(sv, fv, xv), byv);
                        }
                        TR[(jj * 16 + li) * 132 + ml] = v;
                    }
            }
            __syncthreads();
#pragma unroll
            for (int p = 0; p < 8; ++p) {
                const int ol = tid >> 2;
                const int q = (tid & 3) + 4 * p;
                const int m = mb + 4 * q;
                if (m < Mn) {
                    const f32x4 v = *(const f32x4*)&TR[ol * 132 + 4 * q];
                    *(f32x4*)(dst_f32 + ((size_t)b * Cn + h * 64 + ol) * Mn + m) = v;
                }
            }
            __syncthreads();
        }
    }
}

// ---------------------------------------------------------------------------
// Covariance from featt/xt [b][m][c] bf16: raw second moments per (b,g) +
// per-channel sums of f, f^2, f*x, x, x^2.  grid (CVSPLIT, Bn), 256 thr.
// ---------------------------------------------------------------------------
constexpr int CVSPLIT = 8;
constexpr int CVSEG = Mn / CVSPLIT;   // 500

__launch_bounds__(256)
__global__ void cov_kernel(const ushort* __restrict__ featt, const ushort* __restrict__ xt,
                           float* __restrict__ cov,
                           float* __restrict__ sf, float* __restrict__ sf2,
                           float* __restrict__ sfx, float* __restrict__ sx,
                           float* __restrict__ sx2)
{
    __shared__ float fl[64 * 132];
    __shared__ float rs[5][128];
    const int sp = blockIdx.x, b = blockIdx.y;
    const int tid = threadIdx.x;
    const int wv = tid >> 6, l = tid & 63;         // wv = group
    const int i4 = wv * 32 + 4 * (l & 7);
    const int j4 = wv * 32 + 4 * (l >> 3);
    const int sc = tid & 127, sm = tid >> 7;       // sums sweep
    const int m0 = sp * CVSEG;

    float a[4][4];
#pragma unroll
    for (int i = 0; i < 4; ++i)
#pragma unroll
        for (int j = 0; j < 4; ++j) a[i][j] = 0.f;
    float cf = 0.f, cf2 = 0.f, cfx = 0.f, cx = 0.f, cx2 = 0.f;

    for (int t0 = 0; t0 < CVSEG; t0 += 64) {
        const int lim = (CVSEG - t0 < 64) ? (CVSEG - t0) : 64;
        // stage 64m x 128c bf16 -> f32 LDS [m][132]
#pragma unroll
        for (int p = 0; p < 4; ++p) {
            const int u = tid + 256 * p;
            const int mm = u >> 4, c8 = (u & 15) * 8;
            float v[8];
            if (mm < lim) {
                const bf16x8 f8 = *(const bf16x8*)(featt + ((size_t)b * Mn + m0 + t0 + mm) * Cn + c8);
#pragma unroll
                for (int e = 0; e < 8; ++e) v[e] = bf2f((ushort)f8[e]);
            } else {
#pragma unroll
                for (int e = 0; e < 8; ++e) v[e] = 0.f;
            }
#pragma unroll
            for (int e2 = 0; e2 < 4; ++e2)
                *(float2*)&fl[mm * 132 + c8 + 2 * e2] = make_float2(v[2 * e2], v[2 * e2 + 1]);
        }
        __syncthreads();
        // channel sums sweep (f from LDS, x from global)
        for (int mm = sm; mm < lim; mm += 2) {
            const float f = fl[mm * 132 + sc];
            const float xv = bf2f(xt[((size_t)b * Mn + m0 + t0 + mm) * Cn + sc]);
            cf += f; cf2 = fmaf(f, f, cf2); cfx = fmaf(f, xv, cfx);
            cx += xv; cx2 = fmaf(xv, xv, cx2);
        }
        // group covariance products (all 64 lanes same m: broadcast reads)
        for (int mm = 0; mm < lim; ++mm) {
            const float4 fi = *(const float4*)&fl[mm * 132 + i4];
            const float4 fj = *(const float4*)&fl[mm * 132 + j4];
            const float av[4] = {fi.x, fi.y, fi.z, fi.w};
            const float bv[4] = {fj.x, fj.y, fj.z, fj.w};
#pragma unroll
            for (int i = 0; i < 4; ++i)
#pragma unroll
                for (int j = 0; j < 4; ++j)
                    a[i][j] = fmaf(av[i], bv[j], a[i][j]);
        }
        __syncthreads();
    }

    float* cvb = cov + ((size_t)(b * Gn + wv)) * (Dn * Dn);
#pragma unroll
    for (int i = 0; i < 4; ++i)
#pragma unroll
        for (int j = 0; j < 4; ++j)
            atomicAdd(&cvb[(4 * (l & 7) + i) * Dn + 4 * (l >> 3) + j], a[i][j]);

    // channel sums: fold thread t and t+128 (same c), then atomics
    if (tid >= 128) {
        rs[0][sc] = cf; rs[1][sc] = cf2; rs[2][sc] = cfx; rs[3][sc] = cx; rs[4][sc] = cx2;
    }
    __syncthreads();
    if (tid < 128) {
        atomicAdd(&sf[b * Cn + sc],  cf  + rs[0][sc]);
        atomicAdd(&sf2[b * Cn + sc], cf2 + rs[1][sc]);
        atomicAdd(&sfx[b * Cn + sc], cfx + rs[2][sc]);
        atomicAdd(&sx[b * Cn + sc],  cx  + rs[3][sc]);
        atomicAdd(&sx2[b * Cn + sc], cx2 + rs[4][sc]);
    }
}

// ---------------------------------------------------------------------------
// Newton-Schulz sqrtm per (b,g) 32x32 + row-mean -> s[b,c]   (unchanged)
// ---------------------------------------------------------------------------
__device__ __forceinline__ void mm32(float (*A)[33], float (*Bm)[33],
                                     float (*O)[33], int ei, int ej0)
{
    float a0 = 0.f, a1 = 0.f, a2 = 0.f, a3 = 0.f;
#pragma unroll
    for (int k = 0; k < 32; ++k) {
        const float a = A[ei][k];
        a0 = fmaf(a, Bm[k][ej0 + 0], a0);
        a1 = fmaf(a, Bm[k][ej0 + 1], a1);
        a2 = fmaf(a, Bm[k][ej0 + 2], a2);
        a3 = fmaf(a, Bm[k][ej0 + 3], a3);
    }
    O[ei][ej0 + 0] = a0;
    O[ei][ej0 + 1] = a1;
    O[ei][ej0 + 2] = a2;
    O[ei][ej0 + 3] = a3;
    __syncthreads();
}

__launch_bounds__(256)
__global__ void sqrtm_kernel(const float* __restrict__ cov,
                             const float* __restrict__ sf,
                             float* __restrict__ sout)
{
    __shared__ float b0[32][33], b1[32][33], b2[32][33], b3[32][33];
    __shared__ float sh_tr, sh_scale;
    const int bg = blockIdx.x;
    const int b = bg >> 2, g = bg & 3;
    const int tid = threadIdx.x;
    const int ei = (tid * 4) >> 5, ej0 = (tid * 4) & 31;
    const float* cp = cov + (size_t)bg * (Dn * Dn);
    const float* fs = sf + b * Cn + g * Dn;
    const float invM = 1.f / Mn;
    const float mi = fs[ei] * invM;
#pragma unroll
    for (int q = 0; q < 4; ++q)
        b0[ei][ej0 + q] = cp[ei * Dn + ej0 + q] * invM - mi * (fs[ej0 + q] * invM);
    __syncthreads();
    if (tid < 32) {
        float d = b0[tid][tid];
#pragma unroll
        for (int dd = 1; dd < 32; dd <<= 1) d += __shfl_xor(d, dd);
        if (tid == 0) { sh_tr = d; sh_scale = 0.5f * sqrtf(d); }
    }
    __syncthreads();
    const float invtr = 1.f / sh_tr;
#pragma unroll
    for (int q = 0; q < 4; ++q) {
        const float an = b0[ei][ej0 + q] * invtr;
        b0[ei][ej0 + q] = an;
        b1[ei][ej0 + q] = ((ei == ej0 + q) ? 1.5f : 0.f) - 0.5f * an;
    }
    __syncthreads();
    mm32(b0, b1, b2, ei, ej0);  // Y = An @ ZY
    float (*pY)[33] = b2;
    float (*pZ)[33] = b1;
    float (*pF1)[33] = b0;
    float (*pF2)[33] = b3;
#pragma unroll 1
    for (int it = 0; it < 3; ++it) {
        mm32(pZ, pY, pF1, ei, ej0);
#pragma unroll
        for (int q = 0; q < 4; ++q)
            pF1[ei][ej0 + q] = ((ei == ej0 + q) ? 1.5f : 0.f) - 0.5f * pF1[ei][ej0 + q];
        __syncthreads();
        mm32(pY, pF1, pF2, ei, ej0);
        mm32(pF1, pZ, pY, ei, ej0);
        float (*oldZ)[33] = pZ;
        pZ = pY;
        pY = pF2;
        pF2 = oldZ;
    }
    mm32(pZ, pY, pF1, ei, ej0);
#pragma unroll
    for (int q = 0; q < 4; ++q)
        pF1[ei][ej0 + q] = ((ei == ej0 + q) ? 3.f : 0.f) - pF1[ei][ej0 + q];
    __syncthreads();
    mm32(pY, pF1, pF2, ei, ej0);
    if (tid < 32) {
        float t = 0.f;
#pragma unroll
        for (int i = 0; i < 32; ++i) t += pF2[i][tid];
        sout[b * Cn + g * Dn + tid] = t * sh_scale * (1.f / Dn);
    }
}

// ---------------------------------------------------------------------------
// coef1 / coef2 (unchanged analytic affine propagation)
// ---------------------------------------------------------------------------
__launch_bounds__(1024)
__global__ void coef1_kernel(const float* __restrict__ sf, const float* __restrict__ sf2,
                             const float* __restrict__ sfx, const float* __restrict__ sx,
                             const float* __restrict__ sx2, const float* __restrict__ s,
                             const float* __restrict__ gng, const float* __restrict__ gnb,
                             const float* __restrict__ bn1g, const float* __restrict__ bn1b,
                             float* __restrict__ Ay, float* __restrict__ By,
                             float* __restrict__ Ah, float* __restrict__ Bh)
{
    __shared__ float smv[Bn * Cn];
    __shared__ float sm2[Bn * Cn];
    __shared__ float smu[Bn * Gn], srs[Bn * Gn];
    __shared__ float sV[Cn];
    const int tid = threadIdx.x;
    const float invM = 1.f / Mn;
    for (int p = tid; p < Bn * Cn; p += 1024) {
        const float sv = s[p];
        smv[p] = fmaf(sv, sf[p], sx[p]) * invM;
        sm2[p] = (sv * sv * sf2[p] + 2.f * sv * sfx[p] + sx2[p]) * invM;
    }
    __syncthreads();
    if (tid < Bn * Gn) {
        const int base = tid * Dn;
        float mu = 0.f, e2 = 0.f;
        for (int c = 0; c < Dn; ++c) { mu += smv[base + c]; e2 += sm2[base + c]; }
        mu *= (1.f / Dn); e2 *= (1.f / Dn);
        smu[tid] = mu;
        srs[tid] = rsqrtf(e2 - mu * mu + GN_EPS);
    }
    __syncthreads();
    for (int p = tid; p < Bn * Cn; p += 1024) {
        const int c = p & (Cn - 1);
        const int bg = p >> 5;
        const float ay = srs[bg] * gng[c];
        const float mv = smv[p];
        sm2[p] = ay * ay * (sm2[p] - mv * mv);
    }
    __syncthreads();
    if (tid < Cn) {
        float V = 0.f;
        for (int b = 0; b < Bn; ++b) {
            const float vy = sm2[b * Cn + tid];
            V += vy / (vy + IN_EPS);
        }
        sV[tid] = V * (1.f / Bn);
    }
    __syncthreads();
    for (int p = tid; p < Bn * Cn; p += 1024) {
        const int c = p & (Cn - 1);
        const int bg = p >> 5;
        const float ay = srs[bg] * gng[c];
        const float mv = smv[p];
        const float by = gnb[c] - smu[bg] * ay;
        const float rsin = rsqrtf(sm2[p] + IN_EPS);
        const float ah = ay * rsin * rsqrtf(sV[c] + BN_EPS) * bn1g[c];
        const float bh = bn1b[c] - ah * mv;
        Ay[p] = ay; By[p] = by; Ah[p] = ah; Bh[p] = bh;
    }
}

__launch_bounds__(1024)
__global__ void coef2_kernel(const float* __restrict__ sum1, const float* __restrict__ sum2,
                             const float* __restrict__ bn2g, const float* __restrict__ bn2b,
                             float* __restrict__ A2, float* __restrict__ B2)
{
    __shared__ float svar[Bn * Cn];
    __shared__ float sV[Cn];
    const int tid = threadIdx.x;
    const float invM = 1.f / Mn;
    for (int p = tid; p < Bn * Cn; p += 1024) {
        const float mu = sum1[p] * invM;
        svar[p] = sum2[p] * invM - mu * mu;
    }
    __syncthreads();
    if (tid < Cn) {
        float V = 0.f;
        for (int b = 0; b < Bn; ++b) {
            const float v = svar[b * Cn + tid];
            V += v / (v + IN_EPS);
        }
        sV[tid] = V * (1.f / Bn);
    }
    __syncthreads();
    for (int p = tid; p < Bn * Cn; p += 1024) {
        const int c = p & (Cn - 1);
        const float mu = sum1[p] * invM;
        const float a2 = rsqrtf(svar[p] + IN_EPS) * rsqrtf(sV[c] + BN_EPS) * bn2g[c];
        A2[p] = a2;
        B2[p] = bn2b[c] - a2 * mu;
    }
}

// ---------------------------------------------------------------------------
extern "C" void kernel_launch(void* const* d_in, const int* in_sizes, int n_in,
                              void* d_out, int out_size, void* d_ws, size_t ws_size,
                              hipStream_t stream)
{
    const float* x      = (const float*)d_in[0];
    const float* w_lin  = (const float*)d_in[1];
    const float* gn_g   = (const float*)d_in[2];
    const float* gn_b   = (const float*)d_in[3];
    const float* bn1g   = (const float*)d_in[4];
    const float* bn1b   = (const float*)d_in[5];
    const float* conv1w = (const float*)d_in[6];
    const float* conv1b = (const float*)d_in[7];
    const float* bn2g   = (const float*)d_in[8];
    const float* bn2b   = (const float*)d_in[9];
    const float* conv2w = (const float*)d_in[10];
    const float* conv2b = (const float*)d_in[11];
    float* out = (float*)d_out;

    const size_t TS = (size_t)Bn * Mn * Cn;    // 16,384,000 elements
    ushort* xt    = (ushort*)d_ws;
    ushort* featt = xt + TS;
    ushort* h2t   = featt + TS;
    ushort* wb1   = h2t + TS;
    ushort* wb2   = wb1 + Cn * Cn;
    ushort* wb3   = wb2 + Cn * Cn;
    float*  fbase = (float*)(wb3 + Cn * Cn);
    float* sarr = fbase;
    float* Ay   = sarr + Bn * Cn;
    float* By   = Ay + Bn * Cn;
    float* Ah   = By + Bn * Cn;
    float* Bh   = Ah + Bn * Cn;
    float* A2   = Bh + Bn * Cn;
    float* B2   = A2 + Bn * Cn;
    float* zbase = B2 + Bn * Cn;
    float* cov  = zbase;
    float* sf   = cov + Bn * Gn * Dn * Dn;
    float* sf2  = sf + Bn * Cn;
    float* sfx  = sf2 + Bn * Cn;
    float* sx   = sfx + Bn * Cn;
    float* sx2  = sx + Bn * Cn;
    float* sum1 = sx2 + Bn * Cn;
    float* sum2 = sum1 + Bn * Cn;
    const size_t zfloats = (size_t)Bn * Gn * Dn * Dn + 7 * Bn * Cn;

    hipMemsetAsync(zbase, 0, zfloats * sizeof(float), stream);

    prep_w<<<dim3(64), 256, 0, stream>>>(w_lin, wb1);
    prep_w<<<dim3(64), 256, 0, stream>>>(conv1w, wb2);
    prep_w<<<dim3(64), 256, 0, stream>>>(conv2w, wb3);
    prep_xt<<<dim3(Mn / 32, Cn / 32, Bn), 256, 0, stream>>>(x, xt);

    const dim3 ggrid((Mn + 127) / 128, Bn);

    // 1) featt = xt @ W1^T   ([b][m][o] bf16)
    mgemm_kernel<0><<<ggrid, 256, 0, stream>>>(
        wb1, xt, nullptr, featt, nullptr, nullptr, nullptr, nullptr, nullptr,
        nullptr, nullptr, nullptr, nullptr, nullptr, nullptr);

    // 2) covariance + channel sums
    cov_kernel<<<dim3(CVSPLIT, Bn), 256, 0, stream>>>(featt, xt, cov, sf, sf2, sfx, sx, sx2);

    // 3) Newton-Schulz sqrtm -> s
    sqrtm_kernel<<<Bn * Gn, 256, 0, stream>>>(cov, sf, sarr);

    // 4) affine coefficients (GN + first IN/BN/ReLU)
    coef1_kernel<<<1, 1024, 0, stream>>>(sf, sf2, sfx, sx, sx2, sarr,
                                         gn_g, gn_b, bn1g, bn1b, Ay, By, Ah, Bh);

    // 5) h2t = relu(Ah*(s*featt+xt)+Bh) @ W2^T + b1, with stats
    mgemm_kernel<1><<<ggrid, 256, 0, stream>>>(
        wb2, featt, xt, h2t, nullptr, conv1b, sarr, Ah, Bh,
        nullptr, nullptr, nullptr, nullptr, sum1, sum2);

    // 6) second-stage affine coefficients
    coef2_kernel<<<1, 1024, 0, stream>>>(sum1, sum2, bn2g, bn2b, A2, B2);

    // 7) out = relu(A2*h2t+B2) @ W3^T + b2 + y   ([b][o][m] fp32)
    mgemm_kernel<2><<<ggrid, 256, 0, stream>>>(
        wb3, h2t, nullptr, nullptr, out, conv2b, sarr, A2, B2,
        Ay, By, featt, xt, nullptr, nullptr);
}

// Round 4
// 241.810 us; speedup vs baseline: 1.7009x; 1.2083x over previous
//
#include <hip/hip_runtime.h>

constexpr int Bn = 32;
constexpr int Cn = 128;
constexpr int Mn = 4000;
constexpr int Gn = 4;
constexpr int Dn = 32;   // C / G
constexpr float GN_EPS = 1e-5f;
constexpr float IN_EPS = 1e-3f;
constexpr float BN_EPS = 1e-5f;

typedef __attribute__((ext_vector_type(8))) short bf16x8;
typedef __attribute__((ext_vector_type(4))) float f32x4;
typedef __attribute__((ext_vector_type(16))) float f32x16;

__device__ __forceinline__ float bf2f(ushort u) {
    union { unsigned int u; float f; } v;
    v.u = ((unsigned int)u) << 16;
    return v.f;
}
__device__ __forceinline__ ushort f2bf(float f) {
    union { float f; unsigned int u; } v;
    v.f = f;
    unsigned int r = v.u + 0x7FFFu + ((v.u >> 16) & 1u);
    return (ushort)(r >> 16);
}

// ---------------------------------------------------------------------------
// prep_w: fp32 W[128][128] -> bf16 (row-major [o][c])
// ---------------------------------------------------------------------------
__global__ void prep_w(const float* __restrict__ w, ushort* __restrict__ wb) {
    const int i = blockIdx.x * 256 + threadIdx.x;   // 16384 total
    wb[i] = f2bf(w[i]);
}

// ---------------------------------------------------------------------------
// prep_xt: x [b][c][m] fp32 -> xt [b][m][c] bf16 (32x32 LDS tile transpose)
// grid (Mn/32, Cn/32, Bn)
// ---------------------------------------------------------------------------
__launch_bounds__(256)
__global__ void prep_xt(const float* __restrict__ x, ushort* __restrict__ xt) {
    __shared__ float tl[32 * 33];
    const int mb = blockIdx.x * 32, cb = blockIdx.y * 32, b = blockIdx.z;
    const int tid = threadIdx.x;
    const int mi = tid & 31;
#pragma unroll
    for (int p = 0; p < 4; ++p) {
        const int ci = (tid >> 5) + 8 * p;
        tl[ci * 33 + mi] = x[((size_t)b * Cn + cb + ci) * Mn + mb + mi];
    }
    __syncthreads();
#pragma unroll
    for (int p = 0; p < 4; ++p) {
        const int mi2 = (tid >> 5) + 8 * p;
        const int ci2 = tid & 31;
        xt[((size_t)b * Mn + mb + mi2) * Cn + cb + ci2] = f2bf(tl[ci2 * 33 + mi2]);
    }
}

// ---------------------------------------------------------------------------
// MFMA GEMM: D[b][m][o] = sum_c T(src[b][m][c]) * W[o][c]
// MODE 0: T = identity (src=xt)            -> featt bf16 [b][m][o]
// MODE 1: T = relu(tA*(s*f+x)+tB)          -> h2t bf16, +bias, +sum1/sum2
// MODE 2: T = relu(tA*h2+tB)               -> out fp32 [b][o][m], +bias,
//             + y where y = Ay*(s*featt+xt)+By at output coords
// ---------------------------------------------------------------------------
template <int MODE>
__launch_bounds__(256)
__global__ void mgemm_kernel(const ushort* __restrict__ Wb,
                             const ushort* __restrict__ src,
                             const ushort* __restrict__ xsrc,
                             ushort* __restrict__ dst_bf,
                             float* __restrict__ dst_f32,
                             const float* __restrict__ bias,
                             const float* __restrict__ sarr,
                             const float* __restrict__ tA,
                             const float* __restrict__ tB,
                             const float* __restrict__ Ayc,
                             const float* __restrict__ Byc,
                             const ushort* __restrict__ featt,
                             const ushort* __restrict__ xt2,
                             float* __restrict__ sum1,
                             float* __restrict__ sum2)
{
    __shared__ ushort Wl[128 * 136];
    const int b = blockIdx.y;
    const int mb = blockIdx.x * 128;
    const int tid = threadIdx.x;
    const int wv = tid >> 6, l = tid & 63;
    const int li = l & 15, lg = l >> 4;

    // stage W (bf16 [128][128]) -> LDS padded [128][136]
#pragma unroll
    for (int p = 0; p < 8; ++p) {
        const int u = tid + 256 * p;          // 2048 total
        const int o = u >> 4, c8 = (u & 15) * 8;
        *(bf16x8*)&Wl[o * 136 + c8] = *(const bf16x8*)(Wb + o * 128 + c8);
    }
    __syncthreads();

    f32x4 acc[2][8];
#pragma unroll
    for (int t = 0; t < 2; ++t)
#pragma unroll
        for (int j = 0; j < 8; ++j)
#pragma unroll
            for (int r = 0; r < 4; ++r) acc[t][j][r] = 0.f;

#pragma unroll
    for (int kb = 0; kb < 4; ++kb) {
        const int cl = kb * 32 + 8 * lg;      // lane's c-base (8 consecutive c)

        float tAv[8], tBv[8], svv[8];
        if (MODE >= 1) {
            const float4 a0 = *(const float4*)(tA + b * Cn + cl);
            const float4 a1 = *(const float4*)(tA + b * Cn + cl + 4);
            const float4 b0 = *(const float4*)(tB + b * Cn + cl);
            const float4 b1 = *(const float4*)(tB + b * Cn + cl + 4);
            tAv[0]=a0.x; tAv[1]=a0.y; tAv[2]=a0.z; tAv[3]=a0.w;
            tAv[4]=a1.x; tAv[5]=a1.y; tAv[6]=a1.z; tAv[7]=a1.w;
            tBv[0]=b0.x; tBv[1]=b0.y; tBv[2]=b0.z; tBv[3]=b0.w;
            tBv[4]=b1.x; tBv[5]=b1.y; tBv[6]=b1.z; tBv[7]=b1.w;
            if (MODE == 1) {
                const float4 s0 = *(const float4*)(sarr + b * Cn + cl);
                const float4 s1 = *(const float4*)(sarr + b * Cn + cl + 4);
                svv[0]=s0.x; svv[1]=s0.y; svv[2]=s0.z; svv[3]=s0.w;
                svv[4]=s1.x; svv[5]=s1.y; svv[6]=s1.z; svv[7]=s1.w;
            }
        }

        bf16x8 af[2];
#pragma unroll
        for (int t = 0; t < 2; ++t) {
            const int m = mb + wv * 32 + t * 16 + li;
            if (m < Mn) {
                const size_t q = ((size_t)b * Mn + m) * Cn + cl;
                if (MODE == 0) {
                    af[t] = *(const bf16x8*)(src + q);
                } else if (MODE == 1) {
                    const bf16x8 f8 = *(const bf16x8*)(src + q);
                    const bf16x8 x8 = *(const bf16x8*)(xsrc + q);
#pragma unroll
                    for (int e = 0; e < 8; ++e) {
                        const float vv = fmaf(svv[e], bf2f((ushort)f8[e]), bf2f((ushort)x8[e]));
                        af[t][e] = (short)f2bf(fmaxf(fmaf(tAv[e], vv, tBv[e]), 0.f));
                    }
                } else {
                    const bf16x8 f8 = *(const bf16x8*)(src + q);
#pragma unroll
                    for (int e = 0; e < 8; ++e) {
                        const float fv = bf2f((ushort)f8[e]);
                        af[t][e] = (short)f2bf(fmaxf(fmaf(tAv[e], fv, tBv[e]), 0.f));
                    }
                }
            } else {
#pragma unroll
                for (int e = 0; e < 8; ++e) af[t][e] = 0;
            }
        }

#pragma unroll
        for (int j = 0; j < 8; ++j) {
            const bf16x8 bj = *(const bf16x8*)&Wl[(j * 16 + li) * 136 + cl];
            acc[0][j] = __builtin_amdgcn_mfma_f32_16x16x32_bf16(af[0], bj, acc[0][j], 0, 0, 0);
            acc[1][j] = __builtin_amdgcn_mfma_f32_16x16x32_bf16(af[1], bj, acc[1][j], 0, 0, 0);
        }
    }

    // ---------------- epilogues ----------------
    if (MODE == 0) {
#pragma unroll
        for (int j = 0; j < 8; ++j) {
            const int o = j * 16 + li;
#pragma unroll
            for (int t = 0; t < 2; ++t)
#pragma unroll
                for (int r = 0; r < 4; ++r) {
                    const int m = mb + wv * 32 + t * 16 + lg * 4 + r;
                    if (m < Mn)
                        dst_bf[((size_t)b * Mn + m) * Cn + o] = f2bf(acc[t][j][r]);
                }
        }
    } else if (MODE == 1) {
#pragma unroll
        for (int j = 0; j < 8; ++j) {
            const int o = j * 16 + li;
            const float bv = bias[o];
            float s1 = 0.f, s2 = 0.f;
#pragma unroll
            for (int t = 0; t < 2; ++t)
#pragma unroll
                for (int r = 0; r < 4; ++r) {
                    const int m = mb + wv * 32 + t * 16 + lg * 4 + r;
                    if (m < Mn) {
                        const float v = acc[t][j][r] + bv;
                        dst_bf[((size_t)b * Mn + m) * Cn + o] = f2bf(v);
                        s1 += v;
                        s2 = fmaf(v, v, s2);
                    }
                }
            s1 += __shfl_xor(s1, 16); s1 += __shfl_xor(s1, 32);
            s2 += __shfl_xor(s2, 16); s2 += __shfl_xor(s2, 32);
            if (lg == 0) {
                atomicAdd(&sum1[b * Cn + o], s1);
                atomicAdd(&sum2[b * Cn + o], s2);
            }
        }
    } else {
        // MODE 2: add bias + y, transpose via LDS (aliases Wl), store [o][m] f32
        float* TR = (float*)&Wl[0];   // 64*132*4 = 33792 B <= 34816 B
        __syncthreads();
#pragma unroll
        for (int h = 0; h < 2; ++h) {
#pragma unroll
            for (int jj = 0; jj < 4; ++jj) {
                const int j = h * 4 + jj;
                const int o = j * 16 + li;
                const float bv = bias[o];
                const float sv = sarr[b * Cn + o];
                const float ayv = Ayc[b * Cn + o];
                const float byv = Byc[b * Cn + o];
#pragma unroll
                for (int t = 0; t < 2; ++t)
#pragma unroll
                    for (int r = 0; r < 4; ++r) {
                        const int ml = wv * 32 + t * 16 + lg * 4 + r;
                        const int m = mb + ml;
                        float v = acc[t][j][r] + bv;
                        if (m < Mn) {
                            const size_t q = ((size_t)b * Mn + m) * Cn + o;
                            const float fv = bf2f(featt[q]);
                            const float xv = bf2f(xt2[q]);
                            v += fmaf(ayv, fmaf(sv, fv, xv), byv);
                        }
                        TR[(jj * 16 + li) * 132 + ml] = v;
                    }
            }
            __syncthreads();
#pragma unroll
            for (int p = 0; p < 8; ++p) {
                const int ol = tid >> 2;
                const int q = (tid & 3) + 4 * p;
                const int m = mb + 4 * q;
                if (m < Mn) {
                    const f32x4 v = *(const f32x4*)&TR[ol * 132 + 4 * q];
                    *(f32x4*)(dst_f32 + ((size_t)b * Cn + h * 64 + ol) * Mn + m) = v;
                }
            }
            __syncthreads();
        }
    }
}

// ---------------------------------------------------------------------------
// Covariance via MFMA: cov[b,g] += F F^T over m-range, where the 32x32x16
// MFMA's A and B fragments are the SAME register (lane&31 = channel,
// 8 consecutive m per k-slice).  Also accumulates per-channel sums of
// f, f^2, f*x, x, x^2 during staging (each wave owns a fixed c-octet).
// grid: (CVSPLIT, Gn, Bn), 256 threads = 4 waves.
// ---------------------------------------------------------------------------
constexpr int CVSPLIT = 8;
constexpr int CVSEG = Mn / CVSPLIT;   // 500
constexpr int CVMT = 128;             // m per tile (64 u32 pairs)

__launch_bounds__(256)
__global__ void cov_kernel(const ushort* __restrict__ featt, const ushort* __restrict__ xt,
                           float* __restrict__ cov,
                           float* __restrict__ sf, float* __restrict__ sf2,
                           float* __restrict__ sfx, float* __restrict__ sx,
                           float* __restrict__ sx2)
{
    __shared__ unsigned int tl[32 * 66];   // [c 0..31][mp 0..63], stride 66
    __shared__ float red[4][1040];
    const int sp = blockIdx.x, g = blockIdx.y, b = blockIdx.z;
    const int tid = threadIdx.x;
    const int wv = tid >> 6, l = tid & 63;
    const int c8 = wv * 8;                  // wave-uniform channel octet
    const int m0 = sp * CVSEG;

    f32x16 acc;
#pragma unroll
    for (int i = 0; i < 16; ++i) acc[i] = 0.f;
    float cf[8] = {}, cf2[8] = {}, cfx[8] = {}, cx[8] = {}, cx2[8] = {};

    const int ldaddr = (l & 31) * 66 + ((l >> 5) << 2);  // + mpbase at use

    for (int t0 = 0; t0 < CVSEG; t0 += CVMT) {
        const int lim = (CVSEG - t0 < CVMT) ? (CVSEG - t0) : CVMT;  // 128 or 116
        const int mloc = 2 * l;             // this thread's even m within tile
        unsigned int pk[8];
        if (mloc + 1 < lim) {
            const size_t base = ((size_t)b * Mn + m0 + t0 + mloc) * Cn + g * Dn + c8;
            const bf16x8 f0 = *(const bf16x8*)(featt + base);
            const bf16x8 f1 = *(const bf16x8*)(featt + base + Cn);
            const bf16x8 x0 = *(const bf16x8*)(xt + base);
            const bf16x8 x1 = *(const bf16x8*)(xt + base + Cn);
#pragma unroll
            for (int e = 0; e < 8; ++e) {
                const float fa = bf2f((ushort)f0[e]), fb = bf2f((ushort)f1[e]);
                const float xa = bf2f((ushort)x0[e]), xb = bf2f((ushort)x1[e]);
                cf[e]  += fa + fb;
                cf2[e]  = fmaf(fa, fa, fmaf(fb, fb, cf2[e]));
                cfx[e]  = fmaf(fa, xa, fmaf(fb, xb, cfx[e]));
                cx[e]  += xa + xb;
                cx2[e]  = fmaf(xa, xa, fmaf(xb, xb, cx2[e]));
                pk[e] = (unsigned int)(ushort)f0[e] | ((unsigned int)(ushort)f1[e] << 16);
            }
        } else {
#pragma unroll
            for (int e = 0; e < 8; ++e) pk[e] = 0;
        }
        __syncthreads();   // previous tile's MFMA reads complete
#pragma unroll
        for (int e = 0; e < 8; ++e)
            tl[(c8 + e) * 66 + l] = pk[e];
        __syncthreads();
        // wave wv covers mp in [wv*16, wv*16+16): two 16-m k-steps
#pragma unroll
        for (int s = 0; s < 2; ++s) {
            const int mpb = wv * 16 + s * 8;
            const uint4 rv = *(const uint4*)&tl[ldaddr + mpb];
            bf16x8 fr;
            union { uint4 u; bf16x8 h; } cvt;
            cvt.u = rv;
            fr = cvt.h;
            acc = __builtin_amdgcn_mfma_f32_32x32x16_bf16(fr, fr, acc, 0, 0, 0);
        }
    }

    // cross-wave reduce the 32x32 accumulators, one atomic per entry
#pragma unroll
    for (int i = 0; i < 16; ++i) red[wv][l * 16 + i] = acc[i];
    __syncthreads();
    float* cvb = cov + (size_t)(b * Gn + g) * (Dn * Dn);
    for (int e2 = tid; e2 < 1024; e2 += 256) {
        const int ll = e2 >> 4, reg = e2 & 15;
        const float v = red[0][e2] + red[1][e2] + red[2][e2] + red[3][e2];
        const int i = (reg & 3) + 8 * (reg >> 2) + 4 * (ll >> 5);
        const int j = ll & 31;
        atomicAdd(&cvb[i * Dn + j], v);
    }

    // channel sums: 64-lane reduce (all lanes share c8), lane 0 atomics
#pragma unroll
    for (int e = 0; e < 8; ++e) {
#pragma unroll
        for (int d = 1; d < 64; d <<= 1) {
            cf[e]  += __shfl_xor(cf[e], d);
            cf2[e] += __shfl_xor(cf2[e], d);
            cfx[e] += __shfl_xor(cfx[e], d);
            cx[e]  += __shfl_xor(cx[e], d);
            cx2[e] += __shfl_xor(cx2[e], d);
        }
    }
    if (l == 0) {
        const int ch = b * Cn + g * Dn + c8;
#pragma unroll
        for (int e = 0; e < 8; ++e) {
            atomicAdd(&sf[ch + e],  cf[e]);
            atomicAdd(&sf2[ch + e], cf2[e]);
            atomicAdd(&sfx[ch + e], cfx[e]);
            atomicAdd(&sx[ch + e],  cx[e]);
            atomicAdd(&sx2[ch + e], cx2[e]);
        }
    }
}

// ---------------------------------------------------------------------------
// Newton-Schulz sqrtm per (b,g) 32x32 + row-mean -> s[b,c]
// ---------------------------------------------------------------------------
__device__ __forceinline__ void mm32(float (*A)[33], float (*Bm)[33],
                                     float (*O)[33], int ei, int ej0)
{
    float a0 = 0.f, a1 = 0.f, a2 = 0.f, a3 = 0.f;
#pragma unroll
    for (int k = 0; k < 32; ++k) {
        const float a = A[ei][k];
        a0 = fmaf(a, Bm[k][ej0 + 0], a0);
        a1 = fmaf(a, Bm[k][ej0 + 1], a1);
        a2 = fmaf(a, Bm[k][ej0 + 2], a2);
        a3 = fmaf(a, Bm[k][ej0 + 3], a3);
    }
    O[ei][ej0 + 0] = a0;
    O[ei][ej0 + 1] = a1;
    O[ei][ej0 + 2] = a2;
    O[ei][ej0 + 3] = a3;
    __syncthreads();
}

__launch_bounds__(256)
__global__ void sqrtm_kernel(const float* __restrict__ cov,
                             const float* __restrict__ sf,
                             float* __restrict__ sout)
{
    __shared__ float b0[32][33], b1[32][33], b2[32][33], b3[32][33];
    __shared__ float sh_tr, sh_scale;
    const int bg = blockIdx.x;
    const int b = bg >> 2, g = bg & 3;
    const int tid = threadIdx.x;
    const int ei = (tid * 4) >> 5, ej0 = (tid * 4) & 31;
    const float* cp = cov + (size_t)bg * (Dn * Dn);
    const float* fs = sf + b * Cn + g * Dn;
    const float invM = 1.f / Mn;
    const float mi = fs[ei] * invM;
#pragma unroll
    for (int q = 0; q < 4; ++q)
        b0[ei][ej0 + q] = cp[ei * Dn + ej0 + q] * invM - mi * (fs[ej0 + q] * invM);
    __syncthreads();
    if (tid < 32) {
        float d = b0[tid][tid];
#pragma unroll
        for (int dd = 1; dd < 32; dd <<= 1) d += __shfl_xor(d, dd);
        if (tid == 0) { sh_tr = d; sh_scale = 0.5f * sqrtf(d); }
    }
    __syncthreads();
    const float invtr = 1.f / sh_tr;
#pragma unroll
    for (int q = 0; q < 4; ++q) {
        const float an = b0[ei][ej0 + q] * invtr;
        b0[ei][ej0 + q] = an;
        b1[ei][ej0 + q] = ((ei == ej0 + q) ? 1.5f : 0.f) - 0.5f * an;
    }
    __syncthreads();
    mm32(b0, b1, b2, ei, ej0);  // Y = An @ ZY
    float (*pY)[33] = b2;
    float (*pZ)[33] = b1;
    float (*pF1)[33] = b0;
    float (*pF2)[33] = b3;
#pragma unroll 1
    for (int it = 0; it < 3; ++it) {
        mm32(pZ, pY, pF1, ei, ej0);
#pragma unroll
        for (int q = 0; q < 4; ++q)
            pF1[ei][ej0 + q] = ((ei == ej0 + q) ? 1.5f : 0.f) - 0.5f * pF1[ei][ej0 + q];
        __syncthreads();
        mm32(pY, pF1, pF2, ei, ej0);
        mm32(pF1, pZ, pY, ei, ej0);
        float (*oldZ)[33] = pZ;
        pZ = pY;
        pY = pF2;
        pF2 = oldZ;
    }
    mm32(pZ, pY, pF1, ei, ej0);
#pragma unroll
    for (int q = 0; q < 4; ++q)
        pF1[ei][ej0 + q] = ((ei == ej0 + q) ? 3.f : 0.f) - pF1[ei][ej0 + q];
    __syncthreads();
    mm32(pY, pF1, pF2, ei, ej0);
    if (tid < 32) {
        float t = 0.f;
#pragma unroll
        for (int i = 0; i < 32; ++i) t += pF2[i][tid];
        sout[b * Cn + g * Dn + tid] = t * sh_scale * (1.f / Dn);
    }
}

// ---------------------------------------------------------------------------
// coef1 / coef2 (analytic affine propagation)
// ---------------------------------------------------------------------------
__launch_bounds__(1024)
__global__ void coef1_kernel(const float* __restrict__ sf, const float* __restrict__ sf2,
                             const float* __restrict__ sfx, const float* __restrict__ sx,
                             const float* __restrict__ sx2, const float* __restrict__ s,
                             const float* __restrict__ gng, const float* __restrict__ gnb,
                             const float* __restrict__ bn1g, const float* __restrict__ bn1b,
                             float* __restrict__ Ay, float* __restrict__ By,
                             float* __restrict__ Ah, float* __restrict__ Bh)
{
    __shared__ float smv[Bn * Cn];
    __shared__ float sm2[Bn * Cn];
    __shared__ float smu[Bn * Gn], srs[Bn * Gn];
    __shared__ float sV[Cn];
    const int tid = threadIdx.x;
    const float invM = 1.f / Mn;
    for (int p = tid; p < Bn * Cn; p += 1024) {
        const float sv = s[p];
        smv[p] = fmaf(sv, sf[p], sx[p]) * invM;
        sm2[p] = (sv * sv * sf2[p] + 2.f * sv * sfx[p] + sx2[p]) * invM;
    }
    __syncthreads();
    if (tid < Bn * Gn) {
        const int base = tid * Dn;
        float mu = 0.f, e2 = 0.f;
        for (int c = 0; c < Dn; ++c) { mu += smv[base + c]; e2 += sm2[base + c]; }
        mu *= (1.f / Dn); e2 *= (1.f / Dn);
        smu[tid] = mu;
        srs[tid] = rsqrtf(e2 - mu * mu + GN_EPS);
    }
    __syncthreads();
    for (int p = tid; p < Bn * Cn; p += 1024) {
        const int c = p & (Cn - 1);
        const int bg = p >> 5;
        const float ay = srs[bg] * gng[c];
        const float mv = smv[p];
        sm2[p] = ay * ay * (sm2[p] - mv * mv);
    }
    __syncthreads();
    if (tid < Cn) {
        float V = 0.f;
        for (int b = 0; b < Bn; ++b) {
            const float vy = sm2[b * Cn + tid];
            V += vy / (vy + IN_EPS);
        }
        sV[tid] = V * (1.f / Bn);
    }
    __syncthreads();
    for (int p = tid; p < Bn * Cn; p += 1024) {
        const int c = p & (Cn - 1);
        const int bg = p >> 5;
        const float ay = srs[bg] * gng[c];
        const float mv = smv[p];
        const float by = gnb[c] - smu[bg] * ay;
        const float rsin = rsqrtf(sm2[p] + IN_EPS);
        const float ah = ay * rsin * rsqrtf(sV[c] + BN_EPS) * bn1g[c];
        const float bh = bn1b[c] - ah * mv;
        Ay[p] = ay; By[p] = by; Ah[p] = ah; Bh[p] = bh;
    }
}

__launch_bounds__(1024)
__global__ void coef2_kernel(const float* __restrict__ sum1, const float* __restrict__ sum2,
                             const float* __restrict__ bn2g, const float* __restrict__ bn2b,
                             float* __restrict__ A2, float* __restrict__ B2)
{
    __shared__ float svar[Bn * Cn];
    __shared__ float sV[Cn];
    const int tid = threadIdx.x;
    const float invM = 1.f / Mn;
    for (int p = tid; p < Bn * Cn; p += 1024) {
        const float mu = sum1[p] * invM;
        svar[p] = sum2[p] * invM - mu * mu;
    }
    __syncthreads();
    if (tid < Cn) {
        float V = 0.f;
        for (int b = 0; b < Bn; ++b) {
            const float v = svar[b * Cn + tid];
            V += v / (v + IN_EPS);
        }
        sV[tid] = V * (1.f / Bn);
    }
    __syncthreads();
    for (int p = tid; p < Bn * Cn; p += 1024) {
        const int c = p & (Cn - 1);
        const float mu = sum1[p] * invM;
        const float a2 = rsqrtf(svar[p] + IN_EPS) * rsqrtf(sV[c] + BN_EPS) * bn2g[c];
        A2[p] = a2;
        B2[p] = bn2b[c] - a2 * mu;
    }
}

// ---------------------------------------------------------------------------
extern "C" void kernel_launch(void* const* d_in, const int* in_sizes, int n_in,
                              void* d_out, int out_size, void* d_ws, size_t ws_size,
                              hipStream_t stream)
{
    const float* x      = (const float*)d_in[0];
    const float* w_lin  = (const float*)d_in[1];
    const float* gn_g   = (const float*)d_in[2];
    const float* gn_b   = (const float*)d_in[3];
    const float* bn1g   = (const float*)d_in[4];
    const float* bn1b   = (const float*)d_in[5];
    const float* conv1w = (const float*)d_in[6];
    const float* conv1b = (const float*)d_in[7];
    const float* bn2g   = (const float*)d_in[8];
    const float* bn2b   = (const float*)d_in[9];
    const float* conv2w = (const float*)d_in[10];
    const float* conv2b = (const float*)d_in[11];
    float* out = (float*)d_out;

    const size_t TS = (size_t)Bn * Mn * Cn;
    ushort* xt    = (ushort*)d_ws;
    ushort* featt = xt + TS;
    ushort* h2t   = featt + TS;
    ushort* wb1   = h2t + TS;
    ushort* wb2   = wb1 + Cn * Cn;
    ushort* wb3   = wb2 + Cn * Cn;
    float*  fbase = (float*)(wb3 + Cn * Cn);
    float* sarr = fbase;
    float* Ay   = sarr + Bn * Cn;
    float* By   = Ay + Bn * Cn;
    float* Ah   = By + Bn * Cn;
    float* Bh   = Ah + Bn * Cn;
    float* A2   = Bh + Bn * Cn;
    float* B2   = A2 + Bn * Cn;
    float* zbase = B2 + Bn * Cn;
    float* cov  = zbase;
    float* sf   = cov + Bn * Gn * Dn * Dn;
    float* sf2  = sf + Bn * Cn;
    float* sfx  = sf2 + Bn * Cn;
    float* sx   = sfx + Bn * Cn;
    float* sx2  = sx + Bn * Cn;
    float* sum1 = sx2 + Bn * Cn;
    float* sum2 = sum1 + Bn * Cn;
    const size_t zfloats = (size_t)Bn * Gn * Dn * Dn + 7 * Bn * Cn;

    hipMemsetAsync(zbase, 0, zfloats * sizeof(float), stream);

    prep_w<<<dim3(64), 256, 0, stream>>>(w_lin, wb1);
    prep_w<<<dim3(64), 256, 0, stream>>>(conv1w, wb2);
    prep_w<<<dim3(64), 256, 0, stream>>>(conv2w, wb3);
    prep_xt<<<dim3(Mn / 32, Cn / 32, Bn), 256, 0, stream>>>(x, xt);

    const dim3 ggrid((Mn + 127) / 128, Bn);

    // 1) featt = xt @ W1^T   ([b][m][o] bf16)
    mgemm_kernel<0><<<ggrid, 256, 0, stream>>>(
        wb1, xt, nullptr, featt, nullptr, nullptr, nullptr, nullptr, nullptr,
        nullptr, nullptr, nullptr, nullptr, nullptr, nullptr);

    // 2) covariance (MFMA) + channel sums
    cov_kernel<<<dim3(CVSPLIT, Gn, Bn), 256, 0, stream>>>(featt, xt, cov, sf, sf2, sfx, sx, sx2);

    // 3) Newton-Schulz sqrtm -> s
    sqrtm_kernel<<<Bn * Gn, 256, 0, stream>>>(cov, sf, sarr);

    // 4) affine coefficients (GN + first IN/BN/ReLU)
    coef1_kernel<<<1, 1024, 0, stream>>>(sf, sf2, sfx, sx, sx2, sarr,
                                         gn_g, gn_b, bn1g, bn1b, Ay, By, Ah, Bh);

    // 5) h2t = relu(Ah*(s*featt+xt)+Bh) @ W2^T + b1, with stats
    mgemm_kernel<1><<<ggrid, 256, 0, stream>>>(
        wb2, featt, xt, h2t, nullptr, conv1b, sarr, Ah, Bh,
        nullptr, nullptr, nullptr, nullptr, sum1, sum2);

    // 6) second-stage affine coefficients
    coef2_kernel<<<1, 1024, 0, stream>>>(sum1, sum2, bn2g, bn2b, A2, B2);

    // 7) out = relu(A2*h2t+B2) @ W3^T + b2 + y   ([b][o][m] fp32)
    mgemm_kernel<2><<<ggrid, 256, 0, stream>>>(
        wb3, h2t, nullptr, nullptr, out, conv2b, sarr, A2, B2,
        Ay, By, featt, xt, nullptr, nullptr);
}

// Round 5
// 198.361 us; speedup vs baseline: 2.0735x; 1.2190x over previous
//
#include <hip/hip_runtime.h>

constexpr int Bn = 32;
constexpr int Cn = 128;
constexpr int Mn = 4000;
constexpr int Gn = 4;
constexpr int Dn = 32;   // C / G
constexpr float GN_EPS = 1e-5f;
constexpr float IN_EPS = 1e-3f;
constexpr float BN_EPS = 1e-5f;

typedef __attribute__((ext_vector_type(8))) short bf16x8;
typedef __attribute__((ext_vector_type(4))) float f32x4;
typedef __attribute__((ext_vector_type(16))) float f32x16;

__device__ __forceinline__ float bf2f(ushort u) {
    union { unsigned int u; float f; } v;
    v.u = ((unsigned int)u) << 16;
    return v.f;
}
__device__ __forceinline__ ushort f2bf(float f) {
    union { float f; unsigned int u; } v;
    v.f = f;
    unsigned int r = v.u + 0x7FFFu + ((v.u >> 16) & 1u);
    return (ushort)(r >> 16);
}

// ---------------------------------------------------------------------------
// prep_w: fp32 W[128][128] -> bf16 (row-major [o][c])
// ---------------------------------------------------------------------------
__global__ void prep_w(const float* __restrict__ w, ushort* __restrict__ wb) {
    const int i = blockIdx.x * 256 + threadIdx.x;   // 16384 total
    wb[i] = f2bf(w[i]);
}

// ---------------------------------------------------------------------------
// prep_xt: x [b][c][m] fp32 -> xt [b][m][c] bf16 (32x32 LDS tile transpose)
// grid (Mn/32, Cn/32, Bn)
// ---------------------------------------------------------------------------
__launch_bounds__(256)
__global__ void prep_xt(const float* __restrict__ x, ushort* __restrict__ xt) {
    __shared__ float tl[32 * 33];
    const int mb = blockIdx.x * 32, cb = blockIdx.y * 32, b = blockIdx.z;
    const int tid = threadIdx.x;
    const int mi = tid & 31;
#pragma unroll
    for (int p = 0; p < 4; ++p) {
        const int ci = (tid >> 5) + 8 * p;
        tl[ci * 33 + mi] = x[((size_t)b * Cn + cb + ci) * Mn + mb + mi];
    }
    __syncthreads();
#pragma unroll
    for (int p = 0; p < 4; ++p) {
        const int mi2 = (tid >> 5) + 8 * p;
        const int ci2 = tid & 31;
        xt[((size_t)b * Mn + mb + mi2) * Cn + cb + ci2] = f2bf(tl[ci2 * 33 + mi2]);
    }
}

// ---------------------------------------------------------------------------
// MFMA GEMM: D[b][m][o] = sum_c T(src[b][m][c]) * W[o][c]
// MODE 0: T = identity (src=xt)            -> featt bf16 [b][m][o]
// MODE 1: T = relu(tA*(s*f+x)+tB)          -> h2t bf16, +bias, +sum1/sum2,
//             also writes ybuf = Ay*(s*f+x)+By  (bf16 [b][m][c])
// MODE 2: T = relu(tA*h2+tB)               -> out fp32 [b][o][m], +bias,
//             + y read from ybuf via LDS-staged tile
// block: 256 thr = 4 waves; block tile 128m x 128o; grid (ceil(Mn/128), Bn)
// ---------------------------------------------------------------------------
constexpr int WPAD = 140;   // LDS row stride (ushorts): 280B -> banks spread

template <int MODE>
__launch_bounds__(256)
__global__ void mgemm_kernel(const ushort* __restrict__ Wb,
                             const ushort* __restrict__ src,
                             const ushort* __restrict__ xsrc,
                             ushort* __restrict__ dst_bf,
                             float* __restrict__ dst_f32,
                             const float* __restrict__ bias,
                             const float* __restrict__ sarr,
                             const float* __restrict__ tA,
                             const float* __restrict__ tB,
                             const float* __restrict__ Ayc,
                             const float* __restrict__ Byc,
                             ushort* __restrict__ ybuf,
                             float* __restrict__ sum1,
                             float* __restrict__ sum2)
{
    __shared__ ushort Wl[128 * WPAD];
    const int b = blockIdx.y;
    const int mb = blockIdx.x * 128;
    const int tid = threadIdx.x;
    const int wv = tid >> 6, l = tid & 63;
    const int li = l & 15, lg = l >> 4;

    // stage W (bf16 [128][128]) -> LDS padded [128][WPAD]
#pragma unroll
    for (int p = 0; p < 8; ++p) {
        const int u = tid + 256 * p;          // 2048 total
        const int o = u >> 4, c8 = (u & 15) * 8;
        *(bf16x8*)&Wl[o * WPAD + c8] = *(const bf16x8*)(Wb + o * 128 + c8);
    }
    __syncthreads();

    f32x4 acc[2][8];
#pragma unroll
    for (int t = 0; t < 2; ++t)
#pragma unroll
        for (int j = 0; j < 8; ++j)
#pragma unroll
            for (int r = 0; r < 4; ++r) acc[t][j][r] = 0.f;

#pragma unroll
    for (int kb = 0; kb < 4; ++kb) {
        const int cl = kb * 32 + 8 * lg;      // lane's c-base (8 consecutive c)

        float tAv[8], tBv[8], svv[8], ayv[8], byv[8];
        if (MODE >= 1) {
            const float4 a0 = *(const float4*)(tA + b * Cn + cl);
            const float4 a1 = *(const float4*)(tA + b * Cn + cl + 4);
            const float4 b0 = *(const float4*)(tB + b * Cn + cl);
            const float4 b1 = *(const float4*)(tB + b * Cn + cl + 4);
            tAv[0]=a0.x; tAv[1]=a0.y; tAv[2]=a0.z; tAv[3]=a0.w;
            tAv[4]=a1.x; tAv[5]=a1.y; tAv[6]=a1.z; tAv[7]=a1.w;
            tBv[0]=b0.x; tBv[1]=b0.y; tBv[2]=b0.z; tBv[3]=b0.w;
            tBv[4]=b1.x; tBv[5]=b1.y; tBv[6]=b1.z; tBv[7]=b1.w;
            if (MODE == 1) {
                const float4 s0 = *(const float4*)(sarr + b * Cn + cl);
                const float4 s1 = *(const float4*)(sarr + b * Cn + cl + 4);
                svv[0]=s0.x; svv[1]=s0.y; svv[2]=s0.z; svv[3]=s0.w;
                svv[4]=s1.x; svv[5]=s1.y; svv[6]=s1.z; svv[7]=s1.w;
                const float4 y0 = *(const float4*)(Ayc + b * Cn + cl);
                const float4 y1 = *(const float4*)(Ayc + b * Cn + cl + 4);
                const float4 z0 = *(const float4*)(Byc + b * Cn + cl);
                const float4 z1 = *(const float4*)(Byc + b * Cn + cl + 4);
                ayv[0]=y0.x; ayv[1]=y0.y; ayv[2]=y0.z; ayv[3]=y0.w;
                ayv[4]=y1.x; ayv[5]=y1.y; ayv[6]=y1.z; ayv[7]=y1.w;
                byv[0]=z0.x; byv[1]=z0.y; byv[2]=z0.z; byv[3]=z0.w;
                byv[4]=z1.x; byv[5]=z1.y; byv[6]=z1.z; byv[7]=z1.w;
            }
        }

        bf16x8 af[2];
#pragma unroll
        for (int t = 0; t < 2; ++t) {
            const int m = mb + wv * 32 + t * 16 + li;
            if (m < Mn) {
                const size_t q = ((size_t)b * Mn + m) * Cn + cl;
                if (MODE == 0) {
                    af[t] = *(const bf16x8*)(src + q);
                } else if (MODE == 1) {
                    const bf16x8 f8 = *(const bf16x8*)(src + q);
                    const bf16x8 x8 = *(const bf16x8*)(xsrc + q);
                    bf16x8 y8;
#pragma unroll
                    for (int e = 0; e < 8; ++e) {
                        const float vv = fmaf(svv[e], bf2f((ushort)f8[e]), bf2f((ushort)x8[e]));
                        af[t][e] = (short)f2bf(fmaxf(fmaf(tAv[e], vv, tBv[e]), 0.f));
                        y8[e]    = (short)f2bf(fmaf(ayv[e], vv, byv[e]));
                    }
                    *(bf16x8*)(ybuf + q) = y8;
                } else {
                    const bf16x8 f8 = *(const bf16x8*)(src + q);
#pragma unroll
                    for (int e = 0; e < 8; ++e) {
                        const float fv = bf2f((ushort)f8[e]);
                        af[t][e] = (short)f2bf(fmaxf(fmaf(tAv[e], fv, tBv[e]), 0.f));
                    }
                }
            } else {
#pragma unroll
                for (int e = 0; e < 8; ++e) af[t][e] = 0;
            }
        }

#pragma unroll
        for (int j = 0; j < 8; ++j) {
            const bf16x8 bj = *(const bf16x8*)&Wl[(j * 16 + li) * WPAD + cl];
            acc[0][j] = __builtin_amdgcn_mfma_f32_16x16x32_bf16(af[0], bj, acc[0][j], 0, 0, 0);
            acc[1][j] = __builtin_amdgcn_mfma_f32_16x16x32_bf16(af[1], bj, acc[1][j], 0, 0, 0);
        }
    }

    // ---------------- epilogues ----------------
    if (MODE == 0) {
#pragma unroll
        for (int j = 0; j < 8; ++j) {
            const int o = j * 16 + li;
#pragma unroll
            for (int t = 0; t < 2; ++t)
#pragma unroll
                for (int r = 0; r < 4; ++r) {
                    const int m = mb + wv * 32 + t * 16 + lg * 4 + r;
                    if (m < Mn)
                        dst_bf[((size_t)b * Mn + m) * Cn + o] = f2bf(acc[t][j][r]);
                }
        }
    } else if (MODE == 1) {
#pragma unroll
        for (int j = 0; j < 8; ++j) {
            const int o = j * 16 + li;
            const float bv = bias[o];
            float s1 = 0.f, s2 = 0.f;
#pragma unroll
            for (int t = 0; t < 2; ++t)
#pragma unroll
                for (int r = 0; r < 4; ++r) {
                    const int m = mb + wv * 32 + t * 16 + lg * 4 + r;
                    if (m < Mn) {
                        const float v = acc[t][j][r] + bv;
                        dst_bf[((size_t)b * Mn + m) * Cn + o] = f2bf(v);
                        s1 += v;
                        s2 = fmaf(v, v, s2);
                    }
                }
            s1 += __shfl_xor(s1, 16); s1 += __shfl_xor(s1, 32);
            s2 += __shfl_xor(s2, 16); s2 += __shfl_xor(s2, 32);
            if (lg == 0) {
                atomicAdd(&sum1[b * Cn + o], s1);
                atomicAdd(&sum2[b * Cn + o], s2);
            }
        }
    } else {
        // MODE 2: stage y tile into Wl (coalesced), fold bias+y into acc,
        // then LDS-transpose and store [o][m] fp32.
        float* TR = (float*)&Wl[0];   // 64*132*4 = 33792 B <= 128*WPAD*2
        __syncthreads();              // all waves done reading W from Wl
#pragma unroll
        for (int p = 0; p < 8; ++p) {
            const int u = tid + 256 * p;
            const int row = u >> 4, c8 = (u & 15) * 8;
            bf16x8 yv;
            if (mb + row < Mn) {
                yv = *(const bf16x8*)(ybuf + ((size_t)b * Mn + mb + row) * Cn + c8);
            } else {
#pragma unroll
                for (int e = 0; e < 8; ++e) yv[e] = 0;
            }
            *(bf16x8*)&Wl[row * WPAD + c8] = yv;
        }
        __syncthreads();
#pragma unroll
        for (int j = 0; j < 8; ++j) {
            const int o = j * 16 + li;
            const float bv = bias[o];
#pragma unroll
            for (int t = 0; t < 2; ++t)
#pragma unroll
                for (int r = 0; r < 4; ++r) {
                    const int ml = wv * 32 + t * 16 + lg * 4 + r;
                    acc[t][j][r] += bv + bf2f(Wl[ml * WPAD + o]);
                }
        }
        __syncthreads();
#pragma unroll
        for (int h = 0; h < 2; ++h) {
#pragma unroll
            for (int jj = 0; jj < 4; ++jj) {
                const int j = h * 4 + jj;
#pragma unroll
                for (int t = 0; t < 2; ++t)
#pragma unroll
                    for (int r = 0; r < 4; ++r) {
                        const int ml = wv * 32 + t * 16 + lg * 4 + r;
                        TR[(jj * 16 + li) * 132 + ml] = acc[t][j][r];
                    }
            }
            __syncthreads();
#pragma unroll
            for (int p = 0; p < 8; ++p) {
                const int ol = tid >> 2;
                const int q = (tid & 3) + 4 * p;
                const int m = mb + 4 * q;
                if (m < Mn) {
                    const f32x4 v = *(const f32x4*)&TR[ol * 132 + 4 * q];
                    *(f32x4*)(dst_f32 + ((size_t)b * Cn + h * 64 + ol) * Mn + m) = v;
                }
            }
            __syncthreads();
        }
    }
}

// ---------------------------------------------------------------------------
// Covariance via MFMA (A==B fragment trick) + channel sums.
// grid: (CVSPLIT, Gn, Bn), 256 threads = 4 waves.
// ---------------------------------------------------------------------------
constexpr int CVSPLIT = 8;
constexpr int CVSEG = Mn / CVSPLIT;   // 500
constexpr int CVMT = 128;             // m per tile (64 u32 pairs)

__launch_bounds__(256)
__global__ void cov_kernel(const ushort* __restrict__ featt, const ushort* __restrict__ xt,
                           float* __restrict__ cov,
                           float* __restrict__ sf, float* __restrict__ sf2,
                           float* __restrict__ sfx, float* __restrict__ sx,
                           float* __restrict__ sx2)
{
    __shared__ unsigned int tl[32 * 66];   // [c 0..31][mp 0..63], stride 66
    __shared__ float red[4][1040];
    const int sp = blockIdx.x, g = blockIdx.y, b = blockIdx.z;
    const int tid = threadIdx.x;
    const int wv = tid >> 6, l = tid & 63;
    const int c8 = wv * 8;                  // wave-uniform channel octet
    const int m0 = sp * CVSEG;

    f32x16 acc;
#pragma unroll
    for (int i = 0; i < 16; ++i) acc[i] = 0.f;
    float cf[8] = {}, cf2[8] = {}, cfx[8] = {}, cx[8] = {}, cx2[8] = {};

    const int ldaddr = (l & 31) * 66 + ((l >> 5) << 2);  // + mpbase at use

    for (int t0 = 0; t0 < CVSEG; t0 += CVMT) {
        const int lim = (CVSEG - t0 < CVMT) ? (CVSEG - t0) : CVMT;  // 128 or 116
        const int mloc = 2 * l;             // this thread's even m within tile
        unsigned int pk[8];
        if (mloc + 1 < lim) {
            const size_t base = ((size_t)b * Mn + m0 + t0 + mloc) * Cn + g * Dn + c8;
            const bf16x8 f0 = *(const bf16x8*)(featt + base);
            const bf16x8 f1 = *(const bf16x8*)(featt + base + Cn);
            const bf16x8 x0 = *(const bf16x8*)(xt + base);
            const bf16x8 x1 = *(const bf16x8*)(xt + base + Cn);
#pragma unroll
            for (int e = 0; e < 8; ++e) {
                const float fa = bf2f((ushort)f0[e]), fb = bf2f((ushort)f1[e]);
                const float xa = bf2f((ushort)x0[e]), xb = bf2f((ushort)x1[e]);
                cf[e]  += fa + fb;
                cf2[e]  = fmaf(fa, fa, fmaf(fb, fb, cf2[e]));
                cfx[e]  = fmaf(fa, xa, fmaf(fb, xb, cfx[e]));
                cx[e]  += xa + xb;
                cx2[e]  = fmaf(xa, xa, fmaf(xb, xb, cx2[e]));
                pk[e] = (unsigned int)(ushort)f0[e] | ((unsigned int)(ushort)f1[e] << 16);
            }
        } else {
#pragma unroll
            for (int e = 0; e < 8; ++e) pk[e] = 0;
        }
        __syncthreads();
#pragma unroll
        for (int e = 0; e < 8; ++e)
            tl[(c8 + e) * 66 + l] = pk[e];
        __syncthreads();
#pragma unroll
        for (int s = 0; s < 2; ++s) {
            const int mpb = wv * 16 + s * 8;
            const uint4 rv = *(const uint4*)&tl[ldaddr + mpb];
            union { uint4 u; bf16x8 h; } cvt;
            cvt.u = rv;
            acc = __builtin_amdgcn_mfma_f32_32x32x16_bf16(cvt.h, cvt.h, acc, 0, 0, 0);
        }
    }

#pragma unroll
    for (int i = 0; i < 16; ++i) red[wv][l * 16 + i] = acc[i];
    __syncthreads();
    float* cvb = cov + (size_t)(b * Gn + g) * (Dn * Dn);
    for (int e2 = tid; e2 < 1024; e2 += 256) {
        const int ll = e2 >> 4, reg = e2 & 15;
        const float v = red[0][e2] + red[1][e2] + red[2][e2] + red[3][e2];
        const int i = (reg & 3) + 8 * (reg >> 2) + 4 * (ll >> 5);
        const int j = ll & 31;
        atomicAdd(&cvb[i * Dn + j], v);
    }

#pragma unroll
    for (int e = 0; e < 8; ++e) {
#pragma unroll
        for (int d = 1; d < 64; d <<= 1) {
            cf[e]  += __shfl_xor(cf[e], d);
            cf2[e] += __shfl_xor(cf2[e], d);
            cfx[e] += __shfl_xor(cfx[e], d);
            cx[e]  += __shfl_xor(cx[e], d);
            cx2[e] += __shfl_xor(cx2[e], d);
        }
    }
    if (l == 0) {
        const int ch = b * Cn + g * Dn + c8;
#pragma unroll
        for (int e = 0; e < 8; ++e) {
            atomicAdd(&sf[ch + e],  cf[e]);
            atomicAdd(&sf2[ch + e], cf2[e]);
            atomicAdd(&sfx[ch + e], cfx[e]);
            atomicAdd(&sx[ch + e],  cx[e]);
            atomicAdd(&sx2[ch + e], cx2[e]);
        }
    }
}

// ---------------------------------------------------------------------------
// Newton-Schulz sqrtm per (b,g) 32x32 + row-mean -> s[b,c]
// ---------------------------------------------------------------------------
__device__ __forceinline__ void mm32(float (*A)[33], float (*Bm)[33],
                                     float (*O)[33], int ei, int ej0)
{
    float a0 = 0.f, a1 = 0.f, a2 = 0.f, a3 = 0.f;
#pragma unroll
    for (int k = 0; k < 32; ++k) {
        const float a = A[ei][k];
        a0 = fmaf(a, Bm[k][ej0 + 0], a0);
        a1 = fmaf(a, Bm[k][ej0 + 1], a1);
        a2 = fmaf(a, Bm[k][ej0 + 2], a2);
        a3 = fmaf(a, Bm[k][ej0 + 3], a3);
    }
    O[ei][ej0 + 0] = a0;
    O[ei][ej0 + 1] = a1;
    O[ei][ej0 + 2] = a2;
    O[ei][ej0 + 3] = a3;
    __syncthreads();
}

__launch_bounds__(256)
__global__ void sqrtm_kernel(const float* __restrict__ cov,
                             const float* __restrict__ sf,
                             float* __restrict__ sout)
{
    __shared__ float b0[32][33], b1[32][33], b2[32][33], b3[32][33];
    __shared__ float sh_tr, sh_scale;
    const int bg = blockIdx.x;
    const int b = bg >> 2, g = bg & 3;
    const int tid = threadIdx.x;
    const int ei = (tid * 4) >> 5, ej0 = (tid * 4) & 31;
    const float* cp = cov + (size_t)bg * (Dn * Dn);
    const float* fs = sf + b * Cn + g * Dn;
    const float invM = 1.f / Mn;
    const float mi = fs[ei] * invM;
#pragma unroll
    for (int q = 0; q < 4; ++q)
        b0[ei][ej0 + q] = cp[ei * Dn + ej0 + q] * invM - mi * (fs[ej0 + q] * invM);
    __syncthreads();
    if (tid < 32) {
        float d = b0[tid][tid];
#pragma unroll
        for (int dd = 1; dd < 32; dd <<= 1) d += __shfl_xor(d, dd);
        if (tid == 0) { sh_tr = d; sh_scale = 0.5f * sqrtf(d); }
    }
    __syncthreads();
    const float invtr = 1.f / sh_tr;
#pragma unroll
    for (int q = 0; q < 4; ++q) {
        const float an = b0[ei][ej0 + q] * invtr;
        b0[ei][ej0 + q] = an;
        b1[ei][ej0 + q] = ((ei == ej0 + q) ? 1.5f : 0.f) - 0.5f * an;
    }
    __syncthreads();
    mm32(b0, b1, b2, ei, ej0);  // Y = An @ ZY
    float (*pY)[33] = b2;
    float (*pZ)[33] = b1;
    float (*pF1)[33] = b0;
    float (*pF2)[33] = b3;
#pragma unroll 1
    for (int it = 0; it < 3; ++it) {
        mm32(pZ, pY, pF1, ei, ej0);
#pragma unroll
        for (int q = 0; q < 4; ++q)
            pF1[ei][ej0 + q] = ((ei == ej0 + q) ? 1.5f : 0.f) - 0.5f * pF1[ei][ej0 + q];
        __syncthreads();
        mm32(pY, pF1, pF2, ei, ej0);
        mm32(pF1, pZ, pY, ei, ej0);
        float (*oldZ)[33] = pZ;
        pZ = pY;
        pY = pF2;
        pF2 = oldZ;
    }
    mm32(pZ, pY, pF1, ei, ej0);
#pragma unroll
    for (int q = 0; q < 4; ++q)
        pF1[ei][ej0 + q] = ((ei == ej0 + q) ? 3.f : 0.f) - pF1[ei][ej0 + q];
    __syncthreads();
    mm32(pY, pF1, pF2, ei, ej0);
    if (tid < 32) {
        float t = 0.f;
#pragma unroll
        for (int i = 0; i < 32; ++i) t += pF2[i][tid];
        sout[b * Cn + g * Dn + tid] = t * sh_scale * (1.f / Dn);
    }
}

// ---------------------------------------------------------------------------
// coef1 / coef2 (analytic affine propagation)
// ---------------------------------------------------------------------------
__launch_bounds__(1024)
__global__ void coef1_kernel(const float* __restrict__ sf, const float* __restrict__ sf2,
                             const float* __restrict__ sfx, const float* __restrict__ sx,
                             const float* __restrict__ sx2, const float* __restrict__ s,
                             const float* __restrict__ gng, const float* __restrict__ gnb,
                             const float* __restrict__ bn1g, const float* __restrict__ bn1b,
                             float* __restrict__ Ay, float* __restrict__ By,
                             float* __restrict__ Ah, float* __restrict__ Bh)
{
    __shared__ float smv[Bn * Cn];
    __shared__ float sm2[Bn * Cn];
    __shared__ float smu[Bn * Gn], srs[Bn * Gn];
    __shared__ float sV[Cn];
    const int tid = threadIdx.x;
    const float invM = 1.f / Mn;
    for (int p = tid; p < Bn * Cn; p += 1024) {
        const float sv = s[p];
        smv[p] = fmaf(sv, sf[p], sx[p]) * invM;
        sm2[p] = (sv * sv * sf2[p] + 2.f * sv * sfx[p] + sx2[p]) * invM;
    }
    __syncthreads();
    if (tid < Bn * Gn) {
        const int base = tid * Dn;
        float mu = 0.f, e2 = 0.f;
        for (int c = 0; c < Dn; ++c) { mu += smv[base + c]; e2 += sm2[base + c]; }
        mu *= (1.f / Dn); e2 *= (1.f / Dn);
        smu[tid] = mu;
        srs[tid] = rsqrtf(e2 - mu * mu + GN_EPS);
    }
    __syncthreads();
    for (int p = tid; p < Bn * Cn; p += 1024) {
        const int c = p & (Cn - 1);
        const int bg = p >> 5;
        const float ay = srs[bg] * gng[c];
        const float mv = smv[p];
        sm2[p] = ay * ay * (sm2[p] - mv * mv);
    }
    __syncthreads();
    if (tid < Cn) {
        float V = 0.f;
        for (int b = 0; b < Bn; ++b) {
            const float vy = sm2[b * Cn + tid];
            V += vy / (vy + IN_EPS);
        }
        sV[tid] = V * (1.f / Bn);
    }
    __syncthreads();
    for (int p = tid; p < Bn * Cn; p += 1024) {
        const int c = p & (Cn - 1);
        const int bg = p >> 5;
        const float ay = srs[bg] * gng[c];
        const float mv = smv[p];
        const float by = gnb[c] - smu[bg] * ay;
        const float rsin = rsqrtf(sm2[p] + IN_EPS);
        const float ah = ay * rsin * rsqrtf(sV[c] + BN_EPS) * bn1g[c];
        const float bh = bn1b[c] - ah * mv;
        Ay[p] = ay; By[p] = by; Ah[p] = ah; Bh[p] = bh;
    }
}

__launch_bounds__(1024)
__global__ void coef2_kernel(const float* __restrict__ sum1, const float* __restrict__ sum2,
                             const float* __restrict__ bn2g, const float* __restrict__ bn2b,
                             float* __restrict__ A2, float* __restrict__ B2)
{
    __shared__ float svar[Bn * Cn];
    __shared__ float sV[Cn];
    const int tid = threadIdx.x;
    const float invM = 1.f / Mn;
    for (int p = tid; p < Bn * Cn; p += 1024) {
        const float mu = sum1[p] * invM;
        svar[p] = sum2[p] * invM - mu * mu;
    }
    __syncthreads();
    if (tid < Cn) {
        float V = 0.f;
        for (int b = 0; b < Bn; ++b) {
            const float v = svar[b * Cn + tid];
            V += v / (v + IN_EPS);
        }
        sV[tid] = V * (1.f / Bn);
    }
    __syncthreads();
    for (int p = tid; p < Bn * Cn; p += 1024) {
        const int c = p & (Cn - 1);
        const float mu = sum1[p] * invM;
        const float a2 = rsqrtf(svar[p] + IN_EPS) * rsqrtf(sV[c] + BN_EPS) * bn2g[c];
        A2[p] = a2;
        B2[p] = bn2b[c] - a2 * mu;
    }
}

// ---------------------------------------------------------------------------
extern "C" void kernel_launch(void* const* d_in, const int* in_sizes, int n_in,
                              void* d_out, int out_size, void* d_ws, size_t ws_size,
                              hipStream_t stream)
{
    const float* x      = (const float*)d_in[0];
    const float* w_lin  = (const float*)d_in[1];
    const float* gn_g   = (const float*)d_in[2];
    const float* gn_b   = (const float*)d_in[3];
    const float* bn1g   = (const float*)d_in[4];
    const float* bn1b   = (const float*)d_in[5];
    const float* conv1w = (const float*)d_in[6];
    const float* conv1b = (const float*)d_in[7];
    const float* bn2g   = (const float*)d_in[8];
    const float* bn2b   = (const float*)d_in[9];
    const float* conv2w = (const float*)d_in[10];
    const float* conv2b = (const float*)d_in[11];
    float* out = (float*)d_out;

    const size_t TS = (size_t)Bn * Mn * Cn;
    ushort* xt    = (ushort*)d_ws;
    ushort* featt = xt + TS;
    ushort* h2t   = featt + TS;
    ushort* ybuf  = h2t + TS;
    ushort* wb1   = ybuf + TS;
    ushort* wb2   = wb1 + Cn * Cn;
    ushort* wb3   = wb2 + Cn * Cn;
    float*  fbase = (float*)(wb3 + Cn * Cn);
    float* sarr = fbase;
    float* Ay   = sarr + Bn * Cn;
    float* By   = Ay + Bn * Cn;
    float* Ah   = By + Bn * Cn;
    float* Bh   = Ah + Bn * Cn;
    float* A2   = Bh + Bn * Cn;
    float* B2   = A2 + Bn * Cn;
    float* zbase = B2 + Bn * Cn;
    float* cov  = zbase;
    float* sf   = cov + Bn * Gn * Dn * Dn;
    float* sf2  = sf + Bn * Cn;
    float* sfx  = sf2 + Bn * Cn;
    float* sx   = sfx + Bn * Cn;
    float* sx2  = sx + Bn * Cn;
    float* sum1 = sx2 + Bn * Cn;
    float* sum2 = sum1 + Bn * Cn;
    const size_t zfloats = (size_t)Bn * Gn * Dn * Dn + 7 * Bn * Cn;

    hipMemsetAsync(zbase, 0, zfloats * sizeof(float), stream);

    prep_w<<<dim3(64), 256, 0, stream>>>(w_lin, wb1);
    prep_w<<<dim3(64), 256, 0, stream>>>(conv1w, wb2);
    prep_w<<<dim3(64), 256, 0, stream>>>(conv2w, wb3);
    prep_xt<<<dim3(Mn / 32, Cn / 32, Bn), 256, 0, stream>>>(x, xt);

    const dim3 ggrid((Mn + 127) / 128, Bn);

    // 1) featt = xt @ W1^T   ([b][m][o] bf16)
    mgemm_kernel<0><<<ggrid, 256, 0, stream>>>(
        wb1, xt, nullptr, featt, nullptr, nullptr, nullptr, nullptr, nullptr,
        nullptr, nullptr, nullptr, nullptr, nullptr);

    // 2) covariance (MFMA) + channel sums
    cov_kernel<<<dim3(CVSPLIT, Gn, Bn), 256, 0, stream>>>(featt, xt, cov, sf, sf2, sfx, sx, sx2);

    // 3) Newton-Schulz sqrtm -> s
    sqrtm_kernel<<<Bn * Gn, 256, 0, stream>>>(cov, sf, sarr);

    // 4) affine coefficients (GN + first IN/BN/ReLU)
    coef1_kernel<<<1, 1024, 0, stream>>>(sf, sf2, sfx, sx, sx2, sarr,
                                         gn_g, gn_b, bn1g, bn1b, Ay, By, Ah, Bh);

    // 5) h2t = relu(Ah*(s*featt+xt)+Bh) @ W2^T + b1, writes ybuf, stats
    mgemm_kernel<1><<<ggrid, 256, 0, stream>>>(
        wb2, featt, xt, h2t, nullptr, conv1b, sarr, Ah, Bh,
        Ay, By, ybuf, sum1, sum2);

    // 6) second-stage affine coefficients
    coef2_kernel<<<1, 1024, 0, stream>>>(sum1, sum2, bn2g, bn2b, A2, B2);

    // 7) out = relu(A2*h2t+B2) @ W3^T + b2 + y   ([b][o][m] fp32)
    mgemm_kernel<2><<<ggrid, 256, 0, stream>>>(
        wb3, h2t, nullptr, nullptr, out, conv2b, nullptr, A2, B2,
        nullptr, nullptr, ybuf, nullptr, nullptr);
}